// Round 1
// baseline (1770.089 us; speedup 1.0000x reference)
//
#include <hip/hip_runtime.h>
#include <math.h>

// FactorizedSpectralConv2d: pruned-DFT + TT contraction, fp32.
//
// Pipeline (all in d_ws, float offsets below):
//   k_twiddle : build DFT twiddle tables (exact integer phase mod 256)
//   k_g       : g[r][j][x][y] = sum_k cc[j,x,k]*dc[k,y]           (2,32,64,64) c64
//   k_stage1  : Y[h][b][c][kw] = sum_w x[b,c,h,w] e^{-2pi i w kw/256}, kw<64
//   k_cgemm   : XF[k][p] = sum_h FH[k][h] Y[h][p]   (k: 128 kept kh rows)
//   k_contract: OF[k][b][o][y] = sum_c xf * (sum_j bc[i,c,j] g[j,mode]) -> ac
//   k_cgemm   : Z[h][q] = sum_k IH[h][k] OF[k][q]   (full 256 h rows)
//   k_invW    : out[b,o,h,w] = sum_kw s_kw/65536 * Re(Z e^{+2pi i kw w/256})
//               (radix-4 symmetry: one pass yields w, w+64, w+128, w+192)

#define TWO_PI 6.28318530717958647692f

namespace {
constexpr int B_ = 4, CIN = 128, COUT = 128, H_ = 256, W_ = 256;
constexpr int KW_ = 64;
constexpr size_t P_ = 32768;            // B*C*KW pixel batch width

// workspace float offsets
constexpr size_t oY  = 0;                     // [256][4][128][64] f2 ; aliased by Z
constexpr size_t oXF = 16777216;              // [128][4][128][64] f2
constexpr size_t oOF = oXF + 8388608;         // [128][4][128][64] f2
constexpr size_t oFW = oOF + 8388608;         // [256][64]  f2  e^{-i}
constexpr size_t oFH = oFW + 32768;           // [128][256] f2  e^{-i}
constexpr size_t oIH = oFH + 65536;           // [256][128] f2  e^{+i}
constexpr size_t oIW = oIH + 65536;           // [64][64]   f2  scaled e^{+i}
constexpr size_t oG  = oIW + 8192;            // [2][32][64][64] f2
constexpr size_t WS_FLOATS = oG + 524288;     // ~137 MB
}

__global__ __launch_bounds__(256) void k_twiddle(float2* __restrict__ ws2, float* __restrict__ wsf) {
    int idx = blockIdx.x * 256 + threadIdx.x;
    if (idx < 16384) {                       // FW[w][kw] = e^{-2pi i w kw/256}
        int w = idx >> 6, kw = idx & 63;
        int ph = (w * kw) & 255;
        float ang = -TWO_PI * (float)ph / 256.0f;
        float s, c; sincosf(ang, &s, &c);
        ((float2*)(wsf + oFW))[idx] = make_float2(c, s);
    } else if (idx < 16384 + 32768) {        // FH[k][h] = e^{-2pi i kh(k) h/256}
        int i2 = idx - 16384;
        int k = i2 >> 8, h = i2 & 255;
        int kh = k + ((k >= 64) ? 128 : 0);
        int ph = (kh * h) & 255;
        float ang = -TWO_PI * (float)ph / 256.0f;
        float s, c; sincosf(ang, &s, &c);
        ((float2*)(wsf + oFH))[i2] = make_float2(c, s);
    } else if (idx < 16384 + 65536) {        // IH[h][k] = e^{+2pi i kh(k) h/256}
        int i3 = idx - 16384 - 32768;
        int h = i3 >> 7, k = i3 & 127;
        int kh = k + ((k >= 64) ? 128 : 0);
        int ph = (kh * h) & 255;
        float ang = TWO_PI * (float)ph / 256.0f;
        float s, c; sincosf(ang, &s, &c);
        ((float2*)(wsf + oIH))[i3] = make_float2(c, s);
    } else if (idx < 16384 + 65536 + 4096) { // IW[kw][w<64], scale s_kw/65536
        int i4 = idx - 16384 - 65536;
        int kw = i4 >> 6, w = i4 & 63;
        int ph = (kw * w) & 255;
        float ang = TWO_PI * (float)ph / 256.0f;
        float s, c; sincosf(ang, &s, &c);
        float sc = ((kw == 0) ? 1.0f : 2.0f) / 65536.0f;
        ((float2*)(wsf + oIW))[i4] = make_float2(sc * c, sc * s);
    }
    (void)ws2;
}

// g[r][j][x][y] = sum_k cc[j,x,k] * dc[k,y]
__global__ __launch_bounds__(256) void k_g(const float* __restrict__ c1, const float* __restrict__ d1,
                                           const float* __restrict__ c2, const float* __restrict__ d2,
                                           float2* __restrict__ G) {
    int idx = blockIdx.x * 256 + threadIdx.x;      // < 262144
    int r = idx >> 17;
    int rem = idx & 131071;
    int j = rem >> 12;
    int xy = rem & 4095;
    int xm = xy >> 6, ym = xy & 63;
    const float* cp = r ? c2 : c1;
    const float* dp = r ? d2 : d1;
    float sr = 0.f, si = 0.f;
    for (int kk = 0; kk < 32; ++kk) {
        float cr = cp[((j * 64 + xm) * 32 + kk) * 2 + 0];
        float ci = cp[((j * 64 + xm) * 32 + kk) * 2 + 1];
        float dr = dp[(kk * 64 + ym) * 2 + 0];
        float di = dp[(kk * 64 + ym) * 2 + 1];
        sr = fmaf(cr, dr, fmaf(-ci, di, sr));
        si = fmaf(cr, di, fmaf( ci, dr, si));
    }
    G[(size_t)(r * 32 + j) * 4096 + xy] = make_float2(sr, si);
}

// Y[h][bc][kw] = sum_w x[bc,h,w] * FW[w][kw] ; 8 rows per workgroup
__global__ __launch_bounds__(256) void k_stage1(const float* __restrict__ x,
                                                const float2* __restrict__ FW,
                                                float2* __restrict__ Y) {
    __shared__ float xs[8 * 256];
    int t = threadIdx.x;
    size_t row0 = (size_t)blockIdx.x * 8;
    const float4* xv = (const float4*)(x + row0 * 256);
    float4* xsv = (float4*)xs;
    xsv[t] = xv[t];
    xsv[t + 256] = xv[t + 256];
    __syncthreads();
    int kw = t & 63, rs = t >> 6;
    const float* xr0 = xs + rs * 256;
    const float* xr1 = xs + (rs + 4) * 256;
    float a0r = 0.f, a0i = 0.f, a1r = 0.f, a1i = 0.f;
#pragma unroll 4
    for (int w = 0; w < 256; ++w) {
        float2 f = FW[w * 64 + kw];
        float v0 = xr0[w], v1 = xr1[w];
        a0r = fmaf(v0, f.x, a0r); a0i = fmaf(v0, f.y, a0i);
        a1r = fmaf(v1, f.x, a1r); a1i = fmaf(v1, f.y, a1i);
    }
    {
        size_t row = row0 + rs;
        int h = (int)(row & 255); int bc = (int)(row >> 8);
        Y[((size_t)h * 512 + bc) * 64 + kw] = make_float2(a0r, a0i);
    }
    {
        size_t row = row0 + rs + 4;
        int h = (int)(row & 255); int bc = (int)(row >> 8);
        Y[((size_t)h * 512 + bc) * 64 + kw] = make_float2(a1r, a1i);
    }
}

// Out[r][p] = sum_s T[r*S+s] * In[s*32768+p]   (complex GEMM, 16 rows/thread)
__global__ __launch_bounds__(256) void k_cgemm(const float2* __restrict__ T,
                                               const float2* __restrict__ In,
                                               float2* __restrict__ Out, int S) {
    int p = blockIdx.x * 64 + (threadIdx.x & 63);
    int r0 = blockIdx.y * 64 + (threadIdx.x >> 6) * 16;
    float ar[16], ai[16];
#pragma unroll
    for (int kk = 0; kk < 16; ++kk) { ar[kk] = 0.f; ai[kk] = 0.f; }
    for (int s = 0; s < S; s += 2) {
        float2 y0 = In[(size_t)s * P_ + p];
        float2 y1 = In[(size_t)(s + 1) * P_ + p];
#pragma unroll
        for (int kk = 0; kk < 16; ++kk) {
            float4 tv = *(const float4*)&T[(size_t)(r0 + kk) * S + s];
            ar[kk] = fmaf(tv.x, y0.x, fmaf(-tv.y, y0.y, ar[kk]));
            ai[kk] = fmaf(tv.x, y0.y, fmaf( tv.y, y0.x, ai[kk]));
            ar[kk] = fmaf(tv.z, y1.x, fmaf(-tv.w, y1.y, ar[kk]));
            ai[kk] = fmaf(tv.z, y1.y, fmaf( tv.w, y1.x, ai[kk]));
        }
    }
#pragma unroll
    for (int kk = 0; kk < 16; ++kk)
        Out[(size_t)(r0 + kk) * P_ + p] = make_float2(ar[kk], ai[kk]);
}

// Per k-row (one of 128 kept kh rows) and 16-mode y-tile:
//   t[i][b][m] = sum_c (sum_j bc[i,c,j] g[j,m]) * xf[b,c,m]   (t in registers)
//   OF[b][o][m] = sum_i ac[o,i] t[i][b][m]
__global__ __launch_bounds__(256) void k_contract(const float2* __restrict__ XF,
                                                  const float2* __restrict__ G,
                                                  const float* __restrict__ a1, const float* __restrict__ b1,
                                                  const float* __restrict__ a2, const float* __restrict__ b2,
                                                  float2* __restrict__ OF) {
    __shared__ float2 gs[32][16];
    __shared__ float2 bcs[64][33];     // +1 pad: conflict-free row reads
    __shared__ float2 xfs[4][16];
    __shared__ float2 ts[64][4][16];
    int t = threadIdx.x;
    int k = blockIdx.x >> 2;
    int y0 = (blockIdx.x & 3) << 4;
    int reg = (k >= 64) ? 1 : 0;
    const float* bp = reg ? b2 : b1;
    const float* ap = reg ? a2 : a1;
    int x = k & 63;

    for (int e = t; e < 512; e += 256) {
        int j = e >> 4, my = e & 15;
        gs[j][my] = G[(size_t)(reg * 32 + j) * 4096 + x * 64 + (y0 + my)];
    }
    __syncthreads();

    int i = t >> 2, mb = (t & 3) << 2;
    float tr[4][4], ti[4][4];          // [mm][b]
#pragma unroll
    for (int mm = 0; mm < 4; ++mm)
#pragma unroll
        for (int bb = 0; bb < 4; ++bb) { tr[mm][bb] = 0.f; ti[mm][bb] = 0.f; }

    for (int c = 0; c < CIN; ++c) {
        {   // stage bc[:, c, :] -> bcs ; 8 float2 per thread
            int q = t & 3;
            const float4* src = (const float4*)(bp + ((size_t)(i * 128 + c) * 32 + q * 8) * 2);
            float4 v0 = src[0], v1 = src[1], v2 = src[2], v3 = src[3];
            float2* dst = &bcs[i][q * 8];
            dst[0] = make_float2(v0.x, v0.y); dst[1] = make_float2(v0.z, v0.w);
            dst[2] = make_float2(v1.x, v1.y); dst[3] = make_float2(v1.z, v1.w);
            dst[4] = make_float2(v2.x, v2.y); dst[5] = make_float2(v2.z, v2.w);
            dst[6] = make_float2(v3.x, v3.y); dst[7] = make_float2(v3.z, v3.w);
        }
        if (t < 64) {
            int bb = t >> 4, my = t & 15;
            xfs[bb][my] = XF[(((size_t)k * 4 + bb) * 128 + c) * 64 + y0 + my];
        }
        __syncthreads();

        float wr[4], wi[4];
#pragma unroll
        for (int mm = 0; mm < 4; ++mm) { wr[mm] = 0.f; wi[mm] = 0.f; }
#pragma unroll 4
        for (int j = 0; j < 32; ++j) {
            float2 bv = bcs[i][j];
            float4 g01 = *(const float4*)&gs[j][mb];
            float4 g23 = *(const float4*)&gs[j][mb + 2];
            wr[0] = fmaf(bv.x, g01.x, fmaf(-bv.y, g01.y, wr[0]));
            wi[0] = fmaf(bv.x, g01.y, fmaf( bv.y, g01.x, wi[0]));
            wr[1] = fmaf(bv.x, g01.z, fmaf(-bv.y, g01.w, wr[1]));
            wi[1] = fmaf(bv.x, g01.w, fmaf( bv.y, g01.z, wi[1]));
            wr[2] = fmaf(bv.x, g23.x, fmaf(-bv.y, g23.y, wr[2]));
            wi[2] = fmaf(bv.x, g23.y, fmaf( bv.y, g23.x, wi[2]));
            wr[3] = fmaf(bv.x, g23.z, fmaf(-bv.y, g23.w, wr[3]));
            wi[3] = fmaf(bv.x, g23.w, fmaf( bv.y, g23.z, wi[3]));
        }
#pragma unroll
        for (int mm = 0; mm < 4; ++mm) {
#pragma unroll
            for (int bb = 0; bb < 4; ++bb) {
                float2 xv = xfs[bb][mb + mm];
                tr[mm][bb] = fmaf(wr[mm], xv.x, fmaf(-wi[mm], xv.y, tr[mm][bb]));
                ti[mm][bb] = fmaf(wr[mm], xv.y, fmaf( wi[mm], xv.x, ti[mm][bb]));
            }
        }
        __syncthreads();
    }

#pragma unroll
    for (int mm = 0; mm < 4; ++mm)
#pragma unroll
        for (int bb = 0; bb < 4; ++bb)
            ts[i][bb][mb + mm] = make_float2(tr[mm][bb], ti[mm][bb]);
    __syncthreads();

    // epilogue: out[b][o][m] = sum_i ac[o,i] * ts[i][b][m]
    int o = t >> 1, m0 = (t & 1) * 8;
    float er[4][8], ei[4][8];
#pragma unroll
    for (int bb = 0; bb < 4; ++bb)
#pragma unroll
        for (int mm = 0; mm < 8; ++mm) { er[bb][mm] = 0.f; ei[bb][mm] = 0.f; }
    const float2* ap2 = (const float2*)ap;
    for (int ii = 0; ii < 64; ++ii) {
        float2 a = ap2[o * 64 + ii];
#pragma unroll
        for (int bb = 0; bb < 4; ++bb) {
            const float2* tp = &ts[ii][bb][m0];
#pragma unroll
            for (int mm = 0; mm < 8; ++mm) {
                float2 tv = tp[mm];
                er[bb][mm] = fmaf(a.x, tv.x, fmaf(-a.y, tv.y, er[bb][mm]));
                ei[bb][mm] = fmaf(a.x, tv.y, fmaf( a.y, tv.x, ei[bb][mm]));
            }
        }
    }
#pragma unroll
    for (int bb = 0; bb < 4; ++bb)
#pragma unroll
        for (int mm = 0; mm < 8; ++mm)
            OF[(((size_t)k * 4 + bb) * 128 + o) * 64 + y0 + m0 + mm] = make_float2(er[bb][mm], ei[bb][mm]);
}

// out[b,o,h,w'] from Z[h][b][o][kw] using radix-4 symmetry over w.
__global__ __launch_bounds__(256) void k_invW(const float2* __restrict__ Z,
                                              const float2* __restrict__ IW,
                                              float* __restrict__ out) {
    __shared__ float2 zs[8][64];
    int t = threadIdx.x;
    size_t row0 = (size_t)blockIdx.x * 8;
    for (int e = t; e < 512; e += 256) {
        int r = e >> 6, kwi = e & 63;
        zs[r][kwi] = Z[(row0 + r) * 64 + kwi];
    }
    __syncthreads();
    int w = t & 63, rs = t >> 6;
#pragma unroll
    for (int pass = 0; pass < 2; ++pass) {
        int r = rs + pass * 4;
        size_t row = row0 + r;
        int h = (int)(row >> 9);
        int rem = (int)(row & 511);
        int b = rem >> 7, o = rem & 127;
        float s0r = 0.f, s0i = 0.f, s1r = 0.f, s1i = 0.f;
        float s2r = 0.f, s2i = 0.f, s3r = 0.f, s3i = 0.f;
        for (int kw = 0; kw < 64; kw += 4) {
            float2 z0 = zs[r][kw + 0], z1 = zs[r][kw + 1];
            float2 z2 = zs[r][kw + 2], z3 = zs[r][kw + 3];
            float2 f0 = IW[(kw + 0) * 64 + w];
            float2 f1 = IW[(kw + 1) * 64 + w];
            float2 f2 = IW[(kw + 2) * 64 + w];
            float2 f3 = IW[(kw + 3) * 64 + w];
            s0r = fmaf(z0.x, f0.x, fmaf(-z0.y, f0.y, s0r));
            s0i = fmaf(z0.x, f0.y, fmaf( z0.y, f0.x, s0i));
            s1r = fmaf(z1.x, f1.x, fmaf(-z1.y, f1.y, s1r));
            s1i = fmaf(z1.x, f1.y, fmaf( z1.y, f1.x, s1i));
            s2r = fmaf(z2.x, f2.x, fmaf(-z2.y, f2.y, s2r));
            s2i = fmaf(z2.x, f2.y, fmaf( z2.y, f2.x, s2i));
            s3r = fmaf(z3.x, f3.x, fmaf(-z3.y, f3.y, s3r));
            s3i = fmaf(z3.x, f3.y, fmaf( z3.y, f3.x, s3i));
        }
        // out[w+64t] = sum_m Re(S_m * i^{m t})
        float o0 = s0r + s1r + s2r + s3r;
        float o1 = s0r - s1i - s2r + s3i;
        float o2 = s0r - s1r + s2r - s3r;
        float o3 = s0r + s1i - s2r - s3i;
        size_t base = (((size_t)(b * 128 + o)) * 256 + h) * 256 + w;
        out[base + 0]   = o0;
        out[base + 64]  = o1;
        out[base + 128] = o2;
        out[base + 192] = o3;
    }
}

extern "C" void kernel_launch(void* const* d_in, const int* in_sizes, int n_in,
                              void* d_out, int out_size, void* d_ws, size_t ws_size,
                              hipStream_t stream) {
    const float* x  = (const float*)d_in[0];
    const float* a1 = (const float*)d_in[1];
    const float* b1 = (const float*)d_in[2];
    const float* c1 = (const float*)d_in[3];
    const float* d1 = (const float*)d_in[4];
    const float* a2 = (const float*)d_in[5];
    const float* b2 = (const float*)d_in[6];
    const float* c2 = (const float*)d_in[7];
    const float* d2 = (const float*)d_in[8];
    float* out = (float*)d_out;
    float* wsf = (float*)d_ws;

    if (ws_size < WS_FLOATS * sizeof(float)) return;  // scratch too small: bail loudly

    float2* Y   = (float2*)(wsf + oY);
    float2* Zb  = (float2*)(wsf + oY);    // Z aliases Y (Y dead after stage2's consumer)
    float2* XF  = (float2*)(wsf + oXF);
    float2* OF  = (float2*)(wsf + oOF);
    float2* FW  = (float2*)(wsf + oFW);
    float2* FH  = (float2*)(wsf + oFH);
    float2* IH  = (float2*)(wsf + oIH);
    float2* IW  = (float2*)(wsf + oIW);
    float2* G   = (float2*)(wsf + oG);

    k_twiddle<<<336, 256, 0, stream>>>((float2*)d_ws, wsf);
    k_g<<<1024, 256, 0, stream>>>(c1, d1, c2, d2, G);
    k_stage1<<<16384, 256, 0, stream>>>(x, FW, Y);
    k_cgemm<<<dim3(512, 2), 256, 0, stream>>>(FH, Y, XF, 256);
    k_contract<<<512, 256, 0, stream>>>(XF, G, a1, b1, a2, b2, OF);
    k_cgemm<<<dim3(512, 4), 256, 0, stream>>>(IH, OF, Zb, 128);
    k_invW<<<16384, 256, 0, stream>>>(Zb, IW, out);

    (void)in_sizes; (void)n_in; (void)out_size;
}

// Round 3
// 878.583 us; speedup vs baseline: 2.0147x; 2.0147x over previous
//
#include <hip/hip_runtime.h>
#include <math.h>

// FactorizedSpectralConv2d: pruned-DFT + TT contraction, fp32.
//
// Pipeline (all in d_ws, float offsets below):
//   k_twiddle : build DFT twiddle tables (exact integer phase mod 256)
//   k_g       : g[r][j][x][y] = sum_k cc[j,x,k]*dc[k,y]           (2,32,64,64) c64
//   k_stage1  : Y[h][b][c][kw] = sum_w x[b,c,h,w] e^{-2pi i w kw/256}, kw<64
//               (LDS-tiled GEMM: FW chunks + x tile staged in LDS)
//   k_cgemm   : XF[k][p] = sum_h FH[k][h] Y[h][p]   (k: 128 kept kh rows)
//               (T chunk staged in LDS; NOTE float2 row = 32 float4 — 8 f4/thread)
//   k_contract: OF[k][b][o][y] = sum_c xf * (sum_j bc[i,c,j] g[j,mode]) -> ac
//   k_cgemm   : Z[h][q] = sum_k IH[h][k] OF[k][q]   (full 256 h rows)
//   k_invW    : out[b,o,h,w] = sum_kw s_kw/65536 * Re(Z e^{+2pi i kw w/256})
//               (radix-4 over w; IW column held in registers)

#define TWO_PI 6.28318530717958647692f

namespace {
constexpr int B_ = 4, CIN = 128, COUT = 128, H_ = 256, W_ = 256;
constexpr int KW_ = 64;
constexpr size_t P_ = 32768;            // B*C*KW pixel batch width

// workspace float offsets
constexpr size_t oY  = 0;                     // [256][4][128][64] f2 ; aliased by Z
constexpr size_t oXF = 16777216;              // [128][4][128][64] f2
constexpr size_t oOF = oXF + 8388608;         // [128][4][128][64] f2
constexpr size_t oFW = oOF + 8388608;         // [256][64]  f2  e^{-i}
constexpr size_t oFH = oFW + 32768;           // [128][256] f2  e^{-i}
constexpr size_t oIH = oFH + 65536;           // [256][128] f2  e^{+i}
constexpr size_t oIW = oIH + 65536;           // [64][64]   f2  scaled e^{+i}
constexpr size_t oG  = oIW + 8192;            // [2][32][64][64] f2
constexpr size_t WS_FLOATS = oG + 524288;     // ~137 MB
}

__global__ __launch_bounds__(256) void k_twiddle(float2* __restrict__ ws2, float* __restrict__ wsf) {
    int idx = blockIdx.x * 256 + threadIdx.x;
    if (idx < 16384) {                       // FW[w][kw] = e^{-2pi i w kw/256}
        int w = idx >> 6, kw = idx & 63;
        int ph = (w * kw) & 255;
        float ang = -TWO_PI * (float)ph / 256.0f;
        float s, c; sincosf(ang, &s, &c);
        ((float2*)(wsf + oFW))[idx] = make_float2(c, s);
    } else if (idx < 16384 + 32768) {        // FH[k][h] = e^{-2pi i kh(k) h/256}
        int i2 = idx - 16384;
        int k = i2 >> 8, h = i2 & 255;
        int kh = k + ((k >= 64) ? 128 : 0);
        int ph = (kh * h) & 255;
        float ang = -TWO_PI * (float)ph / 256.0f;
        float s, c; sincosf(ang, &s, &c);
        ((float2*)(wsf + oFH))[i2] = make_float2(c, s);
    } else if (idx < 16384 + 65536) {        // IH[h][k] = e^{+2pi i kh(k) h/256}
        int i3 = idx - 16384 - 32768;
        int h = i3 >> 7, k = i3 & 127;
        int kh = k + ((k >= 64) ? 128 : 0);
        int ph = (kh * h) & 255;
        float ang = TWO_PI * (float)ph / 256.0f;
        float s, c; sincosf(ang, &s, &c);
        ((float2*)(wsf + oIH))[i3] = make_float2(c, s);
    } else if (idx < 16384 + 65536 + 4096) { // IW[kw][w<64], scale s_kw/65536
        int i4 = idx - 16384 - 65536;
        int kw = i4 >> 6, w = i4 & 63;
        int ph = (kw * w) & 255;
        float ang = TWO_PI * (float)ph / 256.0f;
        float s, c; sincosf(ang, &s, &c);
        float sc = ((kw == 0) ? 1.0f : 2.0f) / 65536.0f;
        ((float2*)(wsf + oIW))[i4] = make_float2(sc * c, sc * s);
    }
    (void)ws2;
}

// g[r][j][x][y] = sum_k cc[j,x,k] * dc[k,y]
__global__ __launch_bounds__(256) void k_g(const float* __restrict__ c1, const float* __restrict__ d1,
                                           const float* __restrict__ c2, const float* __restrict__ d2,
                                           float2* __restrict__ G) {
    int idx = blockIdx.x * 256 + threadIdx.x;      // < 262144
    int r = idx >> 17;
    int rem = idx & 131071;
    int j = rem >> 12;
    int xy = rem & 4095;
    int xm = xy >> 6, ym = xy & 63;
    const float* cp = r ? c2 : c1;
    const float* dp = r ? d2 : d1;
    float sr = 0.f, si = 0.f;
    for (int kk = 0; kk < 32; ++kk) {
        float cr = cp[((j * 64 + xm) * 32 + kk) * 2 + 0];
        float ci = cp[((j * 64 + xm) * 32 + kk) * 2 + 1];
        float dr = dp[(kk * 64 + ym) * 2 + 0];
        float di = dp[(kk * 64 + ym) * 2 + 1];
        sr = fmaf(cr, dr, fmaf(-ci, di, sr));
        si = fmaf(cr, di, fmaf( ci, dr, si));
    }
    G[(size_t)(r * 32 + j) * 4096 + xy] = make_float2(sr, si);
}

// Y[h][bc][kw] = sum_w x[bc,h,w] * FW[w][kw]
// LDS-tiled: block = 64 rows x 64 kw; K-chunks of 64 w with FW chunk + x tile in LDS.
__global__ __launch_bounds__(256) void k_stage1(const float* __restrict__ x,
                                                const float2* __restrict__ FW,
                                                float2* __restrict__ Y) {
    __shared__ __align__(16) float xs[64][68];    // 64 rows x 64-w chunk (+4 pad, rows 16B-aligned)
    __shared__ __align__(16) float2 fws[64 * 64]; // FW chunk [w][kw]
    int t = threadIdx.x;
    size_t row0 = (size_t)blockIdx.x * 64;
    int kw = t & 63, rq = t >> 6;       // rq in [0,4): 16-row group
    float ar[16], ai[16];
#pragma unroll
    for (int kk = 0; kk < 16; ++kk) { ar[kk] = 0.f; ai[kk] = 0.f; }

    for (int ch = 0; ch < 4; ++ch) {
        __syncthreads();                // protect previous chunk's readers
        {   // x tile: thread loads row r = t>>2, 16 floats (4 float4)
            int r = t >> 2, seg = t & 3;
            const float4* src = (const float4*)(x + (row0 + r) * 256 + ch * 64 + seg * 16);
            float4 v0 = src[0], v1 = src[1], v2 = src[2], v3 = src[3];
            float4* dst = (float4*)&xs[r][seg * 16];
            dst[0] = v0; dst[1] = v1; dst[2] = v2; dst[3] = v3;
        }
        {   // FW chunk: contiguous 32KB; 256 threads x 8 float4
            const float4* src = (const float4*)(FW + (size_t)ch * 4096);
            float4* dst = (float4*)fws;
#pragma unroll
            for (int e = 0; e < 8; ++e) dst[t + 256 * e] = src[t + 256 * e];
        }
        __syncthreads();

        for (int w = 0; w < 64; w += 4) {
            float2 f0 = fws[(w + 0) * 64 + kw];
            float2 f1 = fws[(w + 1) * 64 + kw];
            float2 f2v = fws[(w + 2) * 64 + kw];
            float2 f3 = fws[(w + 3) * 64 + kw];
#pragma unroll
            for (int kk = 0; kk < 16; ++kk) {
                float4 xv = *(const float4*)&xs[rq * 16 + kk][w];   // broadcast b128
                ar[kk] = fmaf(xv.x, f0.x, ar[kk]);  ai[kk] = fmaf(xv.x, f0.y, ai[kk]);
                ar[kk] = fmaf(xv.y, f1.x, ar[kk]);  ai[kk] = fmaf(xv.y, f1.y, ai[kk]);
                ar[kk] = fmaf(xv.z, f2v.x, ar[kk]); ai[kk] = fmaf(xv.z, f2v.y, ai[kk]);
                ar[kk] = fmaf(xv.w, f3.x, ar[kk]);  ai[kk] = fmaf(xv.w, f3.y, ai[kk]);
            }
        }
    }
#pragma unroll
    for (int kk = 0; kk < 16; ++kk) {
        size_t row = row0 + rq * 16 + kk;
        int h = (int)(row & 255); int bc = (int)(row >> 8);
        Y[((size_t)h * 512 + bc) * 64 + kw] = make_float2(ar[kk], ai[kk]);
    }
}

// Out[r][p] = sum_s T[r*S+s] * In[s*32768+p]   (complex GEMM, 16 rows/thread)
// T chunk (64 rows x 64 s, float2) staged in LDS: 32 float4 per row = 8 float4/thread.
__global__ __launch_bounds__(256) void k_cgemm(const float2* __restrict__ T,
                                               const float2* __restrict__ In,
                                               float2* __restrict__ Out, int S) {
    __shared__ __align__(16) float2 Ts[64][66];   // +2 f2 pad, rows stay 16B aligned
    int t = threadIdx.x;
    int p = blockIdx.x * 64 + (t & 63);
    int rq = (t >> 6) * 16;
    int rbase = blockIdx.y * 64;
    float ar[16], ai[16];
#pragma unroll
    for (int kk = 0; kk < 16; ++kk) { ar[kk] = 0.f; ai[kk] = 0.f; }

    for (int sc = 0; sc < S; sc += 64) {
        __syncthreads();
        {   // stage T[rbase+r][sc..sc+64): row = 64 f2 = 32 float4; 4 threads x 8 float4
            int r = t >> 2, seg = t & 3;
            const float4* src = (const float4*)(T + (size_t)(rbase + r) * S + sc) + seg * 8;
            float4* dst = (float4*)&Ts[r][0] + seg * 8;
#pragma unroll
            for (int e = 0; e < 8; ++e) dst[e] = src[e];
        }
        __syncthreads();
        for (int s = 0; s < 64; s += 2) {
            float2 y0 = In[(size_t)(sc + s) * P_ + p];
            float2 y1 = In[(size_t)(sc + s + 1) * P_ + p];
#pragma unroll
            for (int kk = 0; kk < 16; ++kk) {
                float4 tv = *(const float4*)&Ts[rq + kk][s];        // broadcast b128
                ar[kk] = fmaf(tv.x, y0.x, fmaf(-tv.y, y0.y, ar[kk]));
                ai[kk] = fmaf(tv.x, y0.y, fmaf( tv.y, y0.x, ai[kk]));
                ar[kk] = fmaf(tv.z, y1.x, fmaf(-tv.w, y1.y, ar[kk]));
                ai[kk] = fmaf(tv.z, y1.y, fmaf( tv.w, y1.x, ai[kk]));
            }
        }
    }
#pragma unroll
    for (int kk = 0; kk < 16; ++kk)
        Out[(size_t)(rbase + rq + kk) * P_ + p] = make_float2(ar[kk], ai[kk]);
}

// Per k-row (one of 128 kept kh rows) and 16-mode y-tile:
//   t[i][b][m] = sum_c (sum_j bc[i,c,j] g[j,m]) * xf[b,c,m]   (t in registers)
//   OF[b][o][m] = sum_i ac[o,i] t[i][b][m]
__global__ __launch_bounds__(256) void k_contract(const float2* __restrict__ XF,
                                                  const float2* __restrict__ G,
                                                  const float* __restrict__ a1, const float* __restrict__ b1,
                                                  const float* __restrict__ a2, const float* __restrict__ b2,
                                                  float2* __restrict__ OF) {
    __shared__ __align__(16) float2 gs[32][16];
    __shared__ __align__(16) float2 bcs[64][33];  // +1 pad: conflict-free row reads
    __shared__ __align__(16) float2 xfs[4][16];
    __shared__ __align__(16) float2 ts[64][4][16];
    int t = threadIdx.x;
    int k = blockIdx.x >> 2;
    int y0 = (blockIdx.x & 3) << 4;
    int reg = (k >= 64) ? 1 : 0;
    const float* bp = reg ? b2 : b1;
    const float* ap = reg ? a2 : a1;
    int x = k & 63;

    for (int e = t; e < 512; e += 256) {
        int j = e >> 4, my = e & 15;
        gs[j][my] = G[(size_t)(reg * 32 + j) * 4096 + x * 64 + (y0 + my)];
    }
    __syncthreads();

    int i = t >> 2, mb = (t & 3) << 2;
    float tr[4][4], ti[4][4];          // [mm][b]
#pragma unroll
    for (int mm = 0; mm < 4; ++mm)
#pragma unroll
        for (int bb = 0; bb < 4; ++bb) { tr[mm][bb] = 0.f; ti[mm][bb] = 0.f; }

    for (int c = 0; c < CIN; ++c) {
        {   // stage bc[:, c, :] -> bcs ; 8 float2 per thread (4 float4)
            int q = t & 3;
            const float4* src = (const float4*)(bp + ((size_t)(i * 128 + c) * 32 + q * 8) * 2);
            float4 v0 = src[0], v1 = src[1], v2 = src[2], v3 = src[3];
            float2* dst = &bcs[i][q * 8];
            dst[0] = make_float2(v0.x, v0.y); dst[1] = make_float2(v0.z, v0.w);
            dst[2] = make_float2(v1.x, v1.y); dst[3] = make_float2(v1.z, v1.w);
            dst[4] = make_float2(v2.x, v2.y); dst[5] = make_float2(v2.z, v2.w);
            dst[6] = make_float2(v3.x, v3.y); dst[7] = make_float2(v3.z, v3.w);
        }
        if (t < 64) {
            int bb = t >> 4, my = t & 15;
            xfs[bb][my] = XF[(((size_t)k * 4 + bb) * 128 + c) * 64 + y0 + my];
        }
        __syncthreads();

        float wr[4], wi[4];
#pragma unroll
        for (int mm = 0; mm < 4; ++mm) { wr[mm] = 0.f; wi[mm] = 0.f; }
#pragma unroll 4
        for (int j = 0; j < 32; ++j) {
            float2 bv = bcs[i][j];
            float4 g01 = *(const float4*)&gs[j][mb];
            float4 g23 = *(const float4*)&gs[j][mb + 2];
            wr[0] = fmaf(bv.x, g01.x, fmaf(-bv.y, g01.y, wr[0]));
            wi[0] = fmaf(bv.x, g01.y, fmaf( bv.y, g01.x, wi[0]));
            wr[1] = fmaf(bv.x, g01.z, fmaf(-bv.y, g01.w, wr[1]));
            wi[1] = fmaf(bv.x, g01.w, fmaf( bv.y, g01.z, wi[1]));
            wr[2] = fmaf(bv.x, g23.x, fmaf(-bv.y, g23.y, wr[2]));
            wi[2] = fmaf(bv.x, g23.y, fmaf( bv.y, g23.x, wi[2]));
            wr[3] = fmaf(bv.x, g23.z, fmaf(-bv.y, g23.w, wr[3]));
            wi[3] = fmaf(bv.x, g23.w, fmaf( bv.y, g23.z, wi[3]));
        }
#pragma unroll
        for (int mm = 0; mm < 4; ++mm) {
#pragma unroll
            for (int bb = 0; bb < 4; ++bb) {
                float2 xv = xfs[bb][mb + mm];
                tr[mm][bb] = fmaf(wr[mm], xv.x, fmaf(-wi[mm], xv.y, tr[mm][bb]));
                ti[mm][bb] = fmaf(wr[mm], xv.y, fmaf( wi[mm], xv.x, ti[mm][bb]));
            }
        }
        __syncthreads();
    }

#pragma unroll
    for (int mm = 0; mm < 4; ++mm)
#pragma unroll
        for (int bb = 0; bb < 4; ++bb)
            ts[i][bb][mb + mm] = make_float2(tr[mm][bb], ti[mm][bb]);
    __syncthreads();

    // epilogue: out[b][o][m] = sum_i ac[o,i] * ts[i][b][m]
    int o = t >> 1, m0 = (t & 1) * 8;
    float er[4][8], ei[4][8];
#pragma unroll
    for (int bb = 0; bb < 4; ++bb)
#pragma unroll
        for (int mm = 0; mm < 8; ++mm) { er[bb][mm] = 0.f; ei[bb][mm] = 0.f; }
    const float2* ap2 = (const float2*)ap;
    for (int ii = 0; ii < 64; ++ii) {
        float2 a = ap2[o * 64 + ii];
#pragma unroll
        for (int bb = 0; bb < 4; ++bb) {
            const float2* tp = &ts[ii][bb][m0];
#pragma unroll
            for (int mm = 0; mm < 8; ++mm) {
                float2 tv = tp[mm];
                er[bb][mm] = fmaf(a.x, tv.x, fmaf(-a.y, tv.y, er[bb][mm]));
                ei[bb][mm] = fmaf(a.x, tv.y, fmaf( a.y, tv.x, ei[bb][mm]));
            }
        }
    }
#pragma unroll
    for (int bb = 0; bb < 4; ++bb)
#pragma unroll
        for (int mm = 0; mm < 8; ++mm)
            OF[(((size_t)k * 4 + bb) * 128 + o) * 64 + y0 + m0 + mm] = make_float2(er[bb][mm], ei[bb][mm]);
}

// out[b,o,h,w'] from Z[h][b][o][kw] using radix-4 symmetry over w.
// IW column for this lane's w held in registers (2 halves); z rows via LDS broadcast.
__global__ __launch_bounds__(256) void k_invW(const float2* __restrict__ Z,
                                              const float2* __restrict__ IW,
                                              float* __restrict__ out) {
    __shared__ __align__(16) float2 zs[16][64];
    int t = threadIdx.x;
    int w = t & 63, rs = t >> 6;
    size_t row0 = (size_t)blockIdx.x * 16;
    {   // 16 rows of Z -> LDS (1024 f2 = 512 float4)
        const float4* src = (const float4*)(Z + row0 * 64);
        float4* dst = (float4*)zs;
        dst[t] = src[t];
        dst[t + 256] = src[t + 256];
    }
    __syncthreads();

    float sr[4][4], si[4][4];   // [pass][class]
#pragma unroll
    for (int pp = 0; pp < 4; ++pp)
#pragma unroll
        for (int m = 0; m < 4; ++m) { sr[pp][m] = 0.f; si[pp][m] = 0.f; }

#pragma unroll
    for (int kwh = 0; kwh < 2; ++kwh) {
        float2 IWr[32];
#pragma unroll
        for (int q = 0; q < 32; ++q) IWr[q] = IW[(kwh * 32 + q) * 64 + w];  // coalesced
#pragma unroll
        for (int pass = 0; pass < 4; ++pass) {
            int r = rs * 4 + pass;
            const float4* zrow = (const float4*)&zs[r][kwh * 32];
#pragma unroll
            for (int q = 0; q < 16; ++q) {
                float4 zq = zrow[q];                 // z[2q], z[2q+1] (broadcast b128)
                float2 f0 = IWr[2 * q], f1 = IWr[2 * q + 1];
                if ((q & 1) == 0) {                  // classes 0,1
                    sr[pass][0] = fmaf(zq.x, f0.x, fmaf(-zq.y, f0.y, sr[pass][0]));
                    si[pass][0] = fmaf(zq.x, f0.y, fmaf( zq.y, f0.x, si[pass][0]));
                    sr[pass][1] = fmaf(zq.z, f1.x, fmaf(-zq.w, f1.y, sr[pass][1]));
                    si[pass][1] = fmaf(zq.z, f1.y, fmaf( zq.w, f1.x, si[pass][1]));
                } else {                             // classes 2,3
                    sr[pass][2] = fmaf(zq.x, f0.x, fmaf(-zq.y, f0.y, sr[pass][2]));
                    si[pass][2] = fmaf(zq.x, f0.y, fmaf( zq.y, f0.x, si[pass][2]));
                    sr[pass][3] = fmaf(zq.z, f1.x, fmaf(-zq.w, f1.y, sr[pass][3]));
                    si[pass][3] = fmaf(zq.z, f1.y, fmaf( zq.w, f1.x, si[pass][3]));
                }
            }
        }
    }

#pragma unroll
    for (int pass = 0; pass < 4; ++pass) {
        int r = rs * 4 + pass;
        size_t row = row0 + r;
        int h = (int)(row >> 9);
        int rem = (int)(row & 511);
        int b = rem >> 7, o = rem & 127;
        float s0r = sr[pass][0], s1r = sr[pass][1], s2r = sr[pass][2], s3r = sr[pass][3];
        float s1i = si[pass][1], s3i = si[pass][3];
        float o0 = s0r + s1r + s2r + s3r;
        float o1 = s0r - s1i - s2r + s3i;
        float o2 = s0r - s1r + s2r - s3r;
        float o3 = s0r + s1i - s2r - s3i;
        size_t base = (((size_t)(b * 128 + o)) * 256 + h) * 256 + w;
        out[base + 0]   = o0;
        out[base + 64]  = o1;
        out[base + 128] = o2;
        out[base + 192] = o3;
    }
}

extern "C" void kernel_launch(void* const* d_in, const int* in_sizes, int n_in,
                              void* d_out, int out_size, void* d_ws, size_t ws_size,
                              hipStream_t stream) {
    const float* x  = (const float*)d_in[0];
    const float* a1 = (const float*)d_in[1];
    const float* b1 = (const float*)d_in[2];
    const float* c1 = (const float*)d_in[3];
    const float* d1 = (const float*)d_in[4];
    const float* a2 = (const float*)d_in[5];
    const float* b2 = (const float*)d_in[6];
    const float* c2 = (const float*)d_in[7];
    const float* d2 = (const float*)d_in[8];
    float* out = (float*)d_out;
    float* wsf = (float*)d_ws;

    if (ws_size < WS_FLOATS * sizeof(float)) return;

    float2* Y   = (float2*)(wsf + oY);
    float2* Zb  = (float2*)(wsf + oY);    // Z aliases Y
    float2* XF  = (float2*)(wsf + oXF);
    float2* OF  = (float2*)(wsf + oOF);
    float2* FW  = (float2*)(wsf + oFW);
    float2* FH  = (float2*)(wsf + oFH);
    float2* IH  = (float2*)(wsf + oIH);
    float2* IW  = (float2*)(wsf + oIW);
    float2* G   = (float2*)(wsf + oG);

    k_twiddle<<<336, 256, 0, stream>>>((float2*)d_ws, wsf);
    k_g<<<1024, 256, 0, stream>>>(c1, d1, c2, d2, G);
    k_stage1<<<2048, 256, 0, stream>>>(x, FW, Y);
    k_cgemm<<<dim3(512, 2), 256, 0, stream>>>(FH, Y, XF, 256);
    k_contract<<<512, 256, 0, stream>>>(XF, G, a1, b1, a2, b2, OF);
    k_cgemm<<<dim3(512, 4), 256, 0, stream>>>(IH, OF, Zb, 128);
    k_invW<<<16384 / 2, 256, 0, stream>>>(Zb, IW, out);

    (void)in_sizes; (void)n_in; (void)out_size;
}

// Round 4
// 574.153 us; speedup vs baseline: 3.0830x; 1.5302x over previous
//
#include <hip/hip_runtime.h>
#include <math.h>

// FactorizedSpectralConv2d: pruned-DFT + TT contraction.
//
// Pipeline (all in d_ws, float offsets below):
//   k_twiddle : build DFT twiddle tables (exact integer phase mod 256)
//   k_g       : g[r][j][x][y] = sum_k cc[j,x,k]*dc[k,y]           (2,32,64,64) c64
//   k_stage1  : Y[h][b][c][kw] = sum_w x[b,c,h,w] e^{-2pi i w kw/256}, kw<64
//   k_cgemm   : XF[k][p] = sum_h FH[k][h] Y[h][p]   (k: 128 kept kh rows)
//   k_prep    : bf16 MFMA fragment tables for b (A-frags) and g (B-frags)
//               (placed in the then-dead Y region; Z overwrites later)
//   k_contract: MFMA w-GEMM (w = b*g per c) + fp32 t-update + a-epilogue
//   k_cgemm   : Z[h][q] = sum_k IH[h][k] OF[k][q]   (full 256 h rows)
//   k_invW    : out = radix-4 inverse W-DFT of Z (scales folded into IW)

#define TWO_PI 6.28318530717958647692f

typedef __attribute__((ext_vector_type(8))) short short8v;   // 8 bf16 (4 VGPRs)
typedef __attribute__((ext_vector_type(4))) float float4v;   // MFMA C/D

namespace {
constexpr int B_ = 4, CIN = 128, COUT = 128, H_ = 256, W_ = 256;
constexpr size_t P_ = 32768;            // B*C*KW pixel batch width

// workspace float offsets
constexpr size_t oY  = 0;                     // [256][4][128][64] f2 ; aliased by Z and by bA/gB
constexpr size_t oXF = 16777216;              // [128][4][128][64] f2
constexpr size_t oOF = oXF + 8388608;         // [128][4][128][64] f2
constexpr size_t oFW = oOF + 8388608;         // [256][64]  f2  e^{-i}
constexpr size_t oFH = oFW + 32768;           // [128][256] f2  e^{-i}
constexpr size_t oIH = oFH + 65536;           // [256][128] f2  e^{+i}
constexpr size_t oIW = oIH + 65536;           // [64][64]   f2  scaled e^{+i}
constexpr size_t oG  = oIW + 8192;            // [2][32][64][64] f2
constexpr size_t WS_FLOATS = oG + 524288;     // ~137 MB
}

__device__ __forceinline__ unsigned short f2bf(float f) {   // RNE float->bf16 bits
    unsigned int u = __float_as_uint(f);
    unsigned int r = (u + 0x7FFFu + ((u >> 16) & 1u)) >> 16;
    return (unsigned short)r;
}

__global__ __launch_bounds__(256) void k_twiddle(float2* __restrict__ ws2, float* __restrict__ wsf) {
    int idx = blockIdx.x * 256 + threadIdx.x;
    if (idx < 16384) {                       // FW[w][kw] = e^{-2pi i w kw/256}
        int w = idx >> 6, kw = idx & 63;
        int ph = (w * kw) & 255;
        float ang = -TWO_PI * (float)ph / 256.0f;
        float s, c; sincosf(ang, &s, &c);
        ((float2*)(wsf + oFW))[idx] = make_float2(c, s);
    } else if (idx < 16384 + 32768) {        // FH[k][h] = e^{-2pi i kh(k) h/256}
        int i2 = idx - 16384;
        int k = i2 >> 8, h = i2 & 255;
        int kh = k + ((k >= 64) ? 128 : 0);
        int ph = (kh * h) & 255;
        float ang = -TWO_PI * (float)ph / 256.0f;
        float s, c; sincosf(ang, &s, &c);
        ((float2*)(wsf + oFH))[i2] = make_float2(c, s);
    } else if (idx < 16384 + 65536) {        // IH[h][k] = e^{+2pi i kh(k) h/256}
        int i3 = idx - 16384 - 32768;
        int h = i3 >> 7, k = i3 & 127;
        int kh = k + ((k >= 64) ? 128 : 0);
        int ph = (kh * h) & 255;
        float ang = TWO_PI * (float)ph / 256.0f;
        float s, c; sincosf(ang, &s, &c);
        ((float2*)(wsf + oIH))[i3] = make_float2(c, s);
    } else if (idx < 16384 + 65536 + 4096) { // IW[kw][w<64], scale s_kw/65536
        int i4 = idx - 16384 - 65536;
        int kw = i4 >> 6, w = i4 & 63;
        int ph = (kw * w) & 255;
        float ang = TWO_PI * (float)ph / 256.0f;
        float s, c; sincosf(ang, &s, &c);
        float sc = ((kw == 0) ? 1.0f : 2.0f) / 65536.0f;
        ((float2*)(wsf + oIW))[i4] = make_float2(sc * c, sc * s);
    }
    (void)ws2;
}

// g[r][j][x][y] = sum_k cc[j,x,k] * dc[k,y]
__global__ __launch_bounds__(256) void k_g(const float* __restrict__ c1, const float* __restrict__ d1,
                                           const float* __restrict__ c2, const float* __restrict__ d2,
                                           float2* __restrict__ G) {
    int idx = blockIdx.x * 256 + threadIdx.x;      // < 262144
    int r = idx >> 17;
    int rem = idx & 131071;
    int j = rem >> 12;
    int xy = rem & 4095;
    int xm = xy >> 6, ym = xy & 63;
    const float* cp = r ? c2 : c1;
    const float* dp = r ? d2 : d1;
    float sr = 0.f, si = 0.f;
    for (int kk = 0; kk < 32; ++kk) {
        float cr = cp[((j * 64 + xm) * 32 + kk) * 2 + 0];
        float ci = cp[((j * 64 + xm) * 32 + kk) * 2 + 1];
        float dr = dp[(kk * 64 + ym) * 2 + 0];
        float di = dp[(kk * 64 + ym) * 2 + 1];
        sr = fmaf(cr, dr, fmaf(-ci, di, sr));
        si = fmaf(cr, di, fmaf( ci, dr, si));
    }
    G[(size_t)(r * 32 + j) * 4096 + xy] = make_float2(sr, si);
}

// bf16 fragment tables:
//  bA[plane(r,i)][reg][itile][c][lane][e]  (A-frag: row=lane&15 -> i, k=8*(lane>>4)+e -> j)
//  gB[plane(r,i,-i)][reg][x][ytile][lane][e] (B-frag: col=lane&15 -> y, k -> j)
__global__ __launch_bounds__(256) void k_prep(const float* __restrict__ b1, const float* __restrict__ b2,
                                              const float2* __restrict__ G,
                                              unsigned short* __restrict__ bA,
                                              unsigned short* __restrict__ gB) {
    size_t idx = (size_t)blockIdx.x * 256 + threadIdx.x;
    if (idx < 1048576) {
        int e     = idx & 7;
        int lane  = (idx >> 3) & 63;
        int c     = (idx >> 9) & 127;
        int itile = (idx >> 16) & 3;
        int reg   = (idx >> 18) & 1;
        int plane = (idx >> 19) & 1;
        int i = itile * 16 + (lane & 15);
        int j = 8 * (lane >> 4) + e;
        const float* bp = reg ? b2 : b1;
        float v = bp[((size_t)(i * 128 + c) * 32 + j) * 2 + plane];
        bA[idx] = f2bf(v);
    } else if (idx < 1048576 + 786432) {
        size_t i2 = idx - 1048576;
        int e     = i2 & 7;
        int lane  = (i2 >> 3) & 63;
        int ytile = (i2 >> 9) & 3;
        int x     = (i2 >> 11) & 63;
        int reg   = (i2 >> 17) & 1;
        int plane = (int)(i2 >> 18);           // 0,1,2
        int y = ytile * 16 + (lane & 15);
        int j = 8 * (lane >> 4) + e;
        float2 gv = G[(size_t)(reg * 32 + j) * 4096 + x * 64 + y];
        float v = (plane == 0) ? gv.x : ((plane == 1) ? gv.y : -gv.y);
        gB[i2] = f2bf(v);
    }
}

// Y[h][bc][kw] = sum_w x[bc,h,w] * FW[w][kw]
// LDS-tiled: block = 64 rows x 64 kw; K-chunks of 64 w with FW chunk + x tile in LDS.
__global__ __launch_bounds__(256) void k_stage1(const float* __restrict__ x,
                                                const float2* __restrict__ FW,
                                                float2* __restrict__ Y) {
    __shared__ __align__(16) float xs[64][68];    // +4 pad, rows 16B-aligned
    __shared__ __align__(16) float2 fws[64 * 64]; // FW chunk [w][kw]
    int t = threadIdx.x;
    size_t row0 = (size_t)blockIdx.x * 64;
    int kw = t & 63, rq = t >> 6;
    float ar[16], ai[16];
#pragma unroll
    for (int kk = 0; kk < 16; ++kk) { ar[kk] = 0.f; ai[kk] = 0.f; }

    for (int ch = 0; ch < 4; ++ch) {
        __syncthreads();
        {   // x tile: thread loads row r = t>>2, 16 floats (4 float4)
            int r = t >> 2, seg = t & 3;
            const float4* src = (const float4*)(x + (row0 + r) * 256 + ch * 64 + seg * 16);
            float4 v0 = src[0], v1 = src[1], v2 = src[2], v3 = src[3];
            float4* dst = (float4*)&xs[r][seg * 16];
            dst[0] = v0; dst[1] = v1; dst[2] = v2; dst[3] = v3;
        }
        {   // FW chunk: contiguous 32KB; 256 threads x 8 float4
            const float4* src = (const float4*)(FW + (size_t)ch * 4096);
            float4* dst = (float4*)fws;
#pragma unroll
            for (int e = 0; e < 8; ++e) dst[t + 256 * e] = src[t + 256 * e];
        }
        __syncthreads();

        for (int w = 0; w < 64; w += 4) {
            float2 f0 = fws[(w + 0) * 64 + kw];
            float2 f1 = fws[(w + 1) * 64 + kw];
            float2 f2v = fws[(w + 2) * 64 + kw];
            float2 f3 = fws[(w + 3) * 64 + kw];
#pragma unroll
            for (int kk = 0; kk < 16; ++kk) {
                float4 xv = *(const float4*)&xs[rq * 16 + kk][w];
                ar[kk] = fmaf(xv.x, f0.x, ar[kk]);  ai[kk] = fmaf(xv.x, f0.y, ai[kk]);
                ar[kk] = fmaf(xv.y, f1.x, ar[kk]);  ai[kk] = fmaf(xv.y, f1.y, ai[kk]);
                ar[kk] = fmaf(xv.z, f2v.x, ar[kk]); ai[kk] = fmaf(xv.z, f2v.y, ai[kk]);
                ar[kk] = fmaf(xv.w, f3.x, ar[kk]);  ai[kk] = fmaf(xv.w, f3.y, ai[kk]);
            }
        }
    }
#pragma unroll
    for (int kk = 0; kk < 16; ++kk) {
        size_t row = row0 + rq * 16 + kk;
        int h = (int)(row & 255); int bc = (int)(row >> 8);
        Y[((size_t)h * 512 + bc) * 64 + kw] = make_float2(ar[kk], ai[kk]);
    }
}

// Out[r][p] = sum_s T[r*S+s] * In[s*32768+p]   (complex GEMM, 16 rows/thread)
__global__ __launch_bounds__(256) void k_cgemm(const float2* __restrict__ T,
                                               const float2* __restrict__ In,
                                               float2* __restrict__ Out, int S) {
    __shared__ __align__(16) float2 Ts[64][66];
    int t = threadIdx.x;
    int p = blockIdx.x * 64 + (t & 63);
    int rq = (t >> 6) * 16;
    int rbase = blockIdx.y * 64;
    float ar[16], ai[16];
#pragma unroll
    for (int kk = 0; kk < 16; ++kk) { ar[kk] = 0.f; ai[kk] = 0.f; }

    for (int sc = 0; sc < S; sc += 64) {
        __syncthreads();
        {   // stage T chunk: row = 64 f2 = 32 float4; 4 threads x 8 float4
            int r = t >> 2, seg = t & 3;
            const float4* src = (const float4*)(T + (size_t)(rbase + r) * S + sc) + seg * 8;
            float4* dst = (float4*)&Ts[r][0] + seg * 8;
#pragma unroll
            for (int e = 0; e < 8; ++e) dst[e] = src[e];
        }
        __syncthreads();
        for (int s = 0; s < 64; s += 2) {
            float2 y0 = In[(size_t)(sc + s) * P_ + p];
            float2 y1 = In[(size_t)(sc + s + 1) * P_ + p];
#pragma unroll
            for (int kk = 0; kk < 16; ++kk) {
                float4 tv = *(const float4*)&Ts[rq + kk][s];
                ar[kk] = fmaf(tv.x, y0.x, fmaf(-tv.y, y0.y, ar[kk]));
                ai[kk] = fmaf(tv.x, y0.y, fmaf( tv.y, y0.x, ai[kk]));
                ar[kk] = fmaf(tv.z, y1.x, fmaf(-tv.w, y1.y, ar[kk]));
                ai[kk] = fmaf(tv.z, y1.y, fmaf( tv.w, y1.x, ai[kk]));
            }
        }
    }
#pragma unroll
    for (int kk = 0; kk < 16; ++kk)
        Out[(size_t)(rbase + rq + kk) * P_ + p] = make_float2(ar[kk], ai[kk]);
}

// MFMA contract. Block = (k, ytile). Wave = itile (16 i-rows). No barriers in c-loop.
//   per c: wr+iwi = (b[i,c,:32]) . (g[:32, y])   via 4 chained 16x16x32 bf16 MFMAs
//   t[i,b,y] += w * xf[b,c,y]  (fp32)
// then a-epilogue through LDS ts.
__global__ __launch_bounds__(256) void k_contract(const float2* __restrict__ XF,
                                                  const unsigned short* __restrict__ bA,
                                                  const unsigned short* __restrict__ gB,
                                                  const float* __restrict__ a1, const float* __restrict__ a2,
                                                  float2* __restrict__ OF) {
    __shared__ __align__(16) float2 ts[64 * 66];   // [i*66 + b*16 + y] (stride-66: 2-way max)
    int t = threadIdx.x;
    int k = blockIdx.x >> 2;
    int ytile = blockIdx.x & 3;
    int y0 = ytile << 4;
    int reg = (k >= 64) ? 1 : 0;
    int x = k & 63;
    int itile = t >> 6, lane = t & 63;
    int ylane = lane & 15, qg = lane >> 4;

    const short8v* gBv = (const short8v*)gB;
    short8v g_r  = gBv[(((size_t)(0 * 2 + reg) * 64 + x) * 4 + ytile) * 64 + lane];
    short8v g_i  = gBv[(((size_t)(1 * 2 + reg) * 64 + x) * 4 + ytile) * 64 + lane];
    short8v g_ni = gBv[(((size_t)(2 * 2 + reg) * 64 + x) * 4 + ytile) * 64 + lane];

    const short8v* bAv = (const short8v*)bA;
    size_t aR = (((size_t)(0 * 2 + reg) * 4 + itile) * 128) * 64 + lane;  // + c*64
    size_t aI = (((size_t)(1 * 2 + reg) * 4 + itile) * 128) * 64 + lane;

    const float2* xfp = XF + (size_t)k * 32768 + y0 + ylane;              // + b*8192 + c*64

    float tr[4][4], ti[4][4];
#pragma unroll
    for (int q = 0; q < 4; ++q)
#pragma unroll
        for (int b = 0; b < 4; ++b) { tr[q][b] = 0.f; ti[q][b] = 0.f; }

#pragma unroll 2
    for (int c = 0; c < 128; ++c) {
        short8v av = bAv[aR + (size_t)c * 64];
        short8v aw = bAv[aI + (size_t)c * 64];
        float4v z4 = {0.f, 0.f, 0.f, 0.f};
        float4v wr = __builtin_amdgcn_mfma_f32_16x16x32_bf16(av, g_r, z4, 0, 0, 0);
        wr = __builtin_amdgcn_mfma_f32_16x16x32_bf16(aw, g_ni, wr, 0, 0, 0);
        float4v wi = __builtin_amdgcn_mfma_f32_16x16x32_bf16(av, g_i, z4, 0, 0, 0);
        wi = __builtin_amdgcn_mfma_f32_16x16x32_bf16(aw, g_r, wi, 0, 0, 0);
#pragma unroll
        for (int b = 0; b < 4; ++b) {
            float2 xv = xfp[(size_t)b * 8192 + (size_t)c * 64];
#pragma unroll
            for (int q = 0; q < 4; ++q) {
                tr[q][b] = fmaf(wr[q], xv.x, fmaf(-wi[q], xv.y, tr[q][b]));
                ti[q][b] = fmaf(wr[q], xv.y, fmaf( wi[q], xv.x, ti[q][b]));
            }
        }
    }

#pragma unroll
    for (int q = 0; q < 4; ++q) {
        int i = itile * 16 + qg * 4 + q;
#pragma unroll
        for (int b = 0; b < 4; ++b)
            ts[i * 66 + b * 16 + ylane] = make_float2(tr[q][b], ti[q][b]);
    }
    __syncthreads();

    // epilogue: out[b][o][m] = sum_i ac[o,i] * ts[i][b][m]
    int o = t >> 1, m0 = (t & 1) * 8;
    const float* ap = reg ? a2 : a1;
    const float2* ap2 = (const float2*)ap;
    float er[4][8], ei[4][8];
#pragma unroll
    for (int bb = 0; bb < 4; ++bb)
#pragma unroll
        for (int mm = 0; mm < 8; ++mm) { er[bb][mm] = 0.f; ei[bb][mm] = 0.f; }
    for (int ii = 0; ii < 64; ++ii) {
        float2 a = ap2[o * 64 + ii];
#pragma unroll
        for (int bb = 0; bb < 4; ++bb) {
            const float2* tp = &ts[ii * 66 + bb * 16 + m0];
#pragma unroll
            for (int mm = 0; mm < 8; ++mm) {
                float2 tv = tp[mm];
                er[bb][mm] = fmaf(a.x, tv.x, fmaf(-a.y, tv.y, er[bb][mm]));
                ei[bb][mm] = fmaf(a.x, tv.y, fmaf( a.y, tv.x, ei[bb][mm]));
            }
        }
    }
#pragma unroll
    for (int bb = 0; bb < 4; ++bb)
#pragma unroll
        for (int mm = 0; mm < 8; ++mm)
            OF[(((size_t)k * 4 + bb) * 128 + o) * 64 + y0 + m0 + mm] = make_float2(er[bb][mm], ei[bb][mm]);
}

// out[b,o,h,w'] from Z[h][b][o][kw] using radix-4 symmetry over w.
__global__ __launch_bounds__(256) void k_invW(const float2* __restrict__ Z,
                                              const float2* __restrict__ IW,
                                              float* __restrict__ out) {
    __shared__ __align__(16) float2 zs[16][64];
    int t = threadIdx.x;
    int w = t & 63, rs = t >> 6;
    size_t row0 = (size_t)blockIdx.x * 16;
    {
        const float4* src = (const float4*)(Z + row0 * 64);
        float4* dst = (float4*)zs;
        dst[t] = src[t];
        dst[t + 256] = src[t + 256];
    }
    __syncthreads();

    float sr[4][4], si[4][4];
#pragma unroll
    for (int pp = 0; pp < 4; ++pp)
#pragma unroll
        for (int m = 0; m < 4; ++m) { sr[pp][m] = 0.f; si[pp][m] = 0.f; }

#pragma unroll
    for (int kwh = 0; kwh < 2; ++kwh) {
        float2 IWr[32];
#pragma unroll
        for (int q = 0; q < 32; ++q) IWr[q] = IW[(kwh * 32 + q) * 64 + w];
#pragma unroll
        for (int pass = 0; pass < 4; ++pass) {
            int r = rs * 4 + pass;
            const float4* zrow = (const float4*)&zs[r][kwh * 32];
#pragma unroll
            for (int q = 0; q < 16; ++q) {
                float4 zq = zrow[q];
                float2 f0 = IWr[2 * q], f1 = IWr[2 * q + 1];
                if ((q & 1) == 0) {
                    sr[pass][0] = fmaf(zq.x, f0.x, fmaf(-zq.y, f0.y, sr[pass][0]));
                    si[pass][0] = fmaf(zq.x, f0.y, fmaf( zq.y, f0.x, si[pass][0]));
                    sr[pass][1] = fmaf(zq.z, f1.x, fmaf(-zq.w, f1.y, sr[pass][1]));
                    si[pass][1] = fmaf(zq.z, f1.y, fmaf( zq.w, f1.x, si[pass][1]));
                } else {
                    sr[pass][2] = fmaf(zq.x, f0.x, fmaf(-zq.y, f0.y, sr[pass][2]));
                    si[pass][2] = fmaf(zq.x, f0.y, fmaf( zq.y, f0.x, si[pass][2]));
                    sr[pass][3] = fmaf(zq.z, f1.x, fmaf(-zq.w, f1.y, sr[pass][3]));
                    si[pass][3] = fmaf(zq.z, f1.y, fmaf( zq.w, f1.x, si[pass][3]));
                }
            }
        }
    }

#pragma unroll
    for (int pass = 0; pass < 4; ++pass) {
        int r = rs * 4 + pass;
        size_t row = row0 + r;
        int h = (int)(row >> 9);
        int rem = (int)(row & 511);
        int b = rem >> 7, o = rem & 127;
        float s0r = sr[pass][0], s1r = sr[pass][1], s2r = sr[pass][2], s3r = sr[pass][3];
        float s1i = si[pass][1], s3i = si[pass][3];
        float o0 = s0r + s1r + s2r + s3r;
        float o1 = s0r - s1i - s2r + s3i;
        float o2 = s0r - s1r + s2r - s3r;
        float o3 = s0r + s1i - s2r - s3i;
        size_t base = (((size_t)(b * 128 + o)) * 256 + h) * 256 + w;
        out[base + 0]   = o0;
        out[base + 64]  = o1;
        out[base + 128] = o2;
        out[base + 192] = o3;
    }
}

extern "C" void kernel_launch(void* const* d_in, const int* in_sizes, int n_in,
                              void* d_out, int out_size, void* d_ws, size_t ws_size,
                              hipStream_t stream) {
    const float* x  = (const float*)d_in[0];
    const float* a1 = (const float*)d_in[1];
    const float* b1 = (const float*)d_in[2];
    const float* c1 = (const float*)d_in[3];
    const float* d1 = (const float*)d_in[4];
    const float* a2 = (const float*)d_in[5];
    const float* b2 = (const float*)d_in[6];
    const float* c2 = (const float*)d_in[7];
    const float* d2 = (const float*)d_in[8];
    float* out = (float*)d_out;
    float* wsf = (float*)d_ws;

    if (ws_size < WS_FLOATS * sizeof(float)) return;

    float2* Y   = (float2*)(wsf + oY);
    float2* Zb  = (float2*)(wsf + oY);    // Z aliases Y
    float2* XF  = (float2*)(wsf + oXF);
    float2* OF  = (float2*)(wsf + oOF);
    float2* FW  = (float2*)(wsf + oFW);
    float2* FH  = (float2*)(wsf + oFH);
    float2* IH  = (float2*)(wsf + oIH);
    float2* IW  = (float2*)(wsf + oIW);
    float2* G   = (float2*)(wsf + oG);
    // bf16 frag tables live in the Y region (dead between cgemm1 and cgemm2)
    unsigned short* bA = (unsigned short*)(wsf + oY);          // 1,048,576 ushort = 2 MB
    unsigned short* gB = bA + 1048576;                         //   786,432 ushort = 1.5 MB

    k_twiddle<<<336, 256, 0, stream>>>((float2*)d_ws, wsf);
    k_g<<<1024, 256, 0, stream>>>(c1, d1, c2, d2, G);
    k_stage1<<<2048, 256, 0, stream>>>(x, FW, Y);
    k_cgemm<<<dim3(512, 2), 256, 0, stream>>>(FH, Y, XF, 256);
    k_prep<<<7168, 256, 0, stream>>>(b1, b2, G, bA, gB);       // Y now dead; safe to overwrite
    k_contract<<<512, 256, 0, stream>>>(XF, bA, gB, a1, a2, OF);
    k_cgemm<<<dim3(512, 4), 256, 0, stream>>>(IH, OF, Zb, 128);
    k_invW<<<16384 / 2, 256, 0, stream>>>(Zb, IW, out);

    (void)in_sizes; (void)n_in; (void)out_size;
}

// Round 5
// 411.345 us; speedup vs baseline: 4.3032x; 1.3958x over previous
//
#include <hip/hip_runtime.h>
#include <math.h>

// FactorizedSpectralConv2d: pruned-DFT + TT contraction, MFMA everywhere matmul-shaped.
//
//   k_twiddle : FW (stage1) + IW (invW) fp32 twiddle tables
//   k_prepT   : split-bf16 MFMA A-fragment tables for FH / IH DFT matrices
//   k_g       : g[r][j][x][y] = sum_k cc[j,x,k]*dc[k,y]
//   k_stage1  : Y (W-DFT of x, kw<64) written as 4 bf16 planes Yt[s/8][p][8] (hi/lo re/im)
//   k_cmfma   : XF[k][p] = sum_h FH[k][h] Yt[h][p]    (split-bf16 complex MFMA)
//   k_prepBG  : bf16 frag tables for b (A) and g (B) of the TT contraction
//   k_contract: MFMA w-GEMM + fp32 t-update + a-epilogue  -> OF fp32
//   k_repack  : OF fp32 -> OFt 4 bf16 planes [k/8][p][8]
//   k_cmfma   : Z[h][q] = sum_k IH[h][k] OFt[k][q]
//   k_invW    : out = radix-4 inverse W-DFT of Z (scales folded into IW)

#define TWO_PI 6.28318530717958647692f

typedef __attribute__((ext_vector_type(8))) short short8v;   // 8 bf16 (4 VGPRs)
typedef __attribute__((ext_vector_type(4))) float float4v;   // MFMA C/D

namespace {
constexpr size_t P_ = 32768;            // B*C*KW pixel batch width

// workspace float offsets
constexpr size_t oYT = 0;                     // Yt: 4 planes [32][32768][8] bf16 = 16.77M floats
                                              //   then bA/gB (prepBG), then Z f2 (cgemm2/invW)
constexpr size_t oXF = 16777216;              // XF f2 33.5MB; later OFt 4 planes [16][32768][8]
constexpr size_t oOF = 25165824;              // OF f2 33.5MB
constexpr size_t oFW = 33554432;              // [256][64] f2
constexpr size_t oAF1 = 33587200;             // FH frags: 196608 shorts = 98304 floats
constexpr size_t oAF2 = 33685504;             // IH frags: 98304 floats
constexpr size_t oIW = 33783808;              // [64][64] f2
constexpr size_t oG  = 33792000;              // [2][32][64][64] f2
constexpr size_t WS_FLOATS = oG + 524288;     // ~137.3 MB
}

__device__ __forceinline__ unsigned short f2bf(float f) {   // RNE float->bf16 bits
    unsigned int u = __float_as_uint(f);
    unsigned int r = (u + 0x7FFFu + ((u >> 16) & 1u)) >> 16;
    return (unsigned short)r;
}
__device__ __forceinline__ float bf2f(unsigned short b) {
    return __uint_as_float(((unsigned int)b) << 16);
}

__global__ __launch_bounds__(256) void k_twiddle(float* __restrict__ wsf) {
    int idx = blockIdx.x * 256 + threadIdx.x;
    if (idx < 16384) {                       // FW[w][kw] = e^{-2pi i w kw/256}
        int w = idx >> 6, kw = idx & 63;
        int ph = (w * kw) & 255;
        float ang = -TWO_PI * (float)ph / 256.0f;
        float s, c; sincosf(ang, &s, &c);
        ((float2*)(wsf + oFW))[idx] = make_float2(c, s);
    } else if (idx < 16384 + 4096) {         // IW[kw][w<64], scale s_kw/65536
        int i4 = idx - 16384;
        int kw = i4 >> 6, w = i4 & 63;
        int ph = (kw * w) & 255;
        float ang = TWO_PI * (float)ph / 256.0f;
        float s, c; sincosf(ang, &s, &c);
        float sc = ((kw == 0) ? 1.0f : 2.0f) / 65536.0f;
        ((float2*)(wsf + oIW))[i4] = make_float2(sc * c, sc * s);
    }
}

// Split-bf16 A-fragment tables for the DFT matrices.
// Layout: AF[pl][kc][rt][lane][e], pl: 0 Trh 1 Trl 2 Tih 3 Til 4 -Tih 5 -Til.
// AF1 = FH (R=128 kept kh rows, S=256 h), AF2 = IH (R=256 h rows, S=128 k).
__global__ __launch_bounds__(256) void k_prepT(unsigned short* __restrict__ AF1,
                                               unsigned short* __restrict__ AF2) {
    int idx = blockIdx.x * 256 + threadIdx.x;      // < 393216
    int tbl = (idx >= 196608);
    int id = tbl ? (idx - 196608) : idx;
    int e = id & 7, lane = (id >> 3) & 63;
    int pl = id >> 15;
    float ang;
    if (!tbl) {
        int rt = (id >> 9) & 7, kc = (id >> 12) & 7;
        int r = rt * 16 + (lane & 15);             // k-row (128)
        int s = kc * 32 + 8 * (lane >> 4) + e;     // h (256)
        int kh = r + ((r >= 64) ? 128 : 0);
        int ph = (kh * s) & 255;
        ang = -TWO_PI * (float)ph / 256.0f;
    } else {
        int rt = (id >> 9) & 15, kc = (id >> 13) & 3;
        int r = rt * 16 + (lane & 15);             // h (256)
        int s = kc * 32 + 8 * (lane >> 4) + e;     // k (128)
        int kh = s + ((s >= 64) ? 128 : 0);
        int ph = (kh * r) & 255;
        ang = TWO_PI * (float)ph / 256.0f;
    }
    float sn, cs; sincosf(ang, &sn, &cs);
    float base = (pl < 2) ? cs : ((pl < 4) ? sn : -sn);
    unsigned short hi = f2bf(base);
    unsigned short out = (pl & 1) ? f2bf(base - bf2f(hi)) : hi;
    (tbl ? AF2 : AF1)[id] = out;
}

// g[r][j][x][y] = sum_k cc[j,x,k] * dc[k,y]
__global__ __launch_bounds__(256) void k_g(const float* __restrict__ c1, const float* __restrict__ d1,
                                           const float* __restrict__ c2, const float* __restrict__ d2,
                                           float2* __restrict__ G) {
    int idx = blockIdx.x * 256 + threadIdx.x;      // < 262144
    int r = idx >> 17;
    int rem = idx & 131071;
    int j = rem >> 12;
    int xy = rem & 4095;
    int xm = xy >> 6, ym = xy & 63;
    const float* cp = r ? c2 : c1;
    const float* dp = r ? d2 : d1;
    float sr = 0.f, si = 0.f;
    for (int kk = 0; kk < 32; ++kk) {
        float cr = cp[((j * 64 + xm) * 32 + kk) * 2 + 0];
        float ci = cp[((j * 64 + xm) * 32 + kk) * 2 + 1];
        float dr = dp[(kk * 64 + ym) * 2 + 0];
        float di = dp[(kk * 64 + ym) * 2 + 1];
        sr = fmaf(cr, dr, fmaf(-ci, di, sr));
        si = fmaf(cr, di, fmaf( ci, dr, si));
    }
    G[(size_t)(r * 32 + j) * 4096 + xy] = make_float2(sr, si);
}

// bf16 fragment tables for the contraction:
//  bA[plane(r,i)][reg][itile][c][lane][e], gB[plane(r,i,-i)][reg][x][ytile][lane][e]
__global__ __launch_bounds__(256) void k_prepBG(const float* __restrict__ b1, const float* __restrict__ b2,
                                                const float2* __restrict__ G,
                                                unsigned short* __restrict__ bA,
                                                unsigned short* __restrict__ gB) {
    size_t idx = (size_t)blockIdx.x * 256 + threadIdx.x;
    if (idx < 1048576) {
        int e     = idx & 7;
        int lane  = (idx >> 3) & 63;
        int c     = (idx >> 9) & 127;
        int itile = (idx >> 16) & 3;
        int reg   = (idx >> 18) & 1;
        int plane = (idx >> 19) & 1;
        int i = itile * 16 + (lane & 15);
        int j = 8 * (lane >> 4) + e;
        const float* bp = reg ? b2 : b1;
        float v = bp[((size_t)(i * 128 + c) * 32 + j) * 2 + plane];
        bA[idx] = f2bf(v);
    } else if (idx < 1048576 + 786432) {
        size_t i2 = idx - 1048576;
        int e     = i2 & 7;
        int lane  = (i2 >> 3) & 63;
        int ytile = (i2 >> 9) & 3;
        int x     = (i2 >> 11) & 63;
        int reg   = (i2 >> 17) & 1;
        int plane = (int)(i2 >> 18);           // 0,1,2
        int y = ytile * 16 + (lane & 15);
        int j = 8 * (lane >> 4) + e;
        float2 gv = G[(size_t)(reg * 32 + j) * 4096 + x * 64 + y];
        float v = (plane == 0) ? gv.x : ((plane == 1) ? gv.y : -gv.y);
        gB[i2] = f2bf(v);
    }
}

// Y[h][bc][kw] = sum_w x[bc,h,w] * FW[w][kw]; output as 4 bf16 planes Yt[h>>3][p][h&7].
__global__ __launch_bounds__(256) void k_stage1(const float* __restrict__ x,
                                                const float2* __restrict__ FW,
                                                unsigned short* __restrict__ Yt) {
    __shared__ __align__(16) float xs[64][68];
    __shared__ __align__(16) float2 fws[64 * 64];
    int t = threadIdx.x;
    size_t row0 = (size_t)blockIdx.x * 64;
    int kw = t & 63, rq = t >> 6;
    float ar[16], ai[16];
#pragma unroll
    for (int kk = 0; kk < 16; ++kk) { ar[kk] = 0.f; ai[kk] = 0.f; }

    for (int ch = 0; ch < 4; ++ch) {
        __syncthreads();
        {
            int r = t >> 2, seg = t & 3;
            const float4* src = (const float4*)(x + (row0 + r) * 256 + ch * 64 + seg * 16);
            float4 v0 = src[0], v1 = src[1], v2 = src[2], v3 = src[3];
            float4* dst = (float4*)&xs[r][seg * 16];
            dst[0] = v0; dst[1] = v1; dst[2] = v2; dst[3] = v3;
        }
        {
            const float4* src = (const float4*)(FW + (size_t)ch * 4096);
            float4* dst = (float4*)fws;
#pragma unroll
            for (int e = 0; e < 8; ++e) dst[t + 256 * e] = src[t + 256 * e];
        }
        __syncthreads();

        for (int w = 0; w < 64; w += 4) {
            float2 f0 = fws[(w + 0) * 64 + kw];
            float2 f1 = fws[(w + 1) * 64 + kw];
            float2 f2v = fws[(w + 2) * 64 + kw];
            float2 f3 = fws[(w + 3) * 64 + kw];
#pragma unroll
            for (int kk = 0; kk < 16; ++kk) {
                float4 xv = *(const float4*)&xs[rq * 16 + kk][w];
                ar[kk] = fmaf(xv.x, f0.x, ar[kk]);  ai[kk] = fmaf(xv.x, f0.y, ai[kk]);
                ar[kk] = fmaf(xv.y, f1.x, ar[kk]);  ai[kk] = fmaf(xv.y, f1.y, ai[kk]);
                ar[kk] = fmaf(xv.z, f2v.x, ar[kk]); ai[kk] = fmaf(xv.z, f2v.y, ai[kk]);
                ar[kk] = fmaf(xv.w, f3.x, ar[kk]);  ai[kk] = fmaf(xv.w, f3.y, ai[kk]);
            }
        }
    }
    // split-bf16 writes: 2 h-groups x 4 planes, each one b128 store, lanes -> consecutive p
    int hfirst = (int)(row0 & 255) + rq * 16;
    int bc = (int)(row0 >> 8);
    size_t p = (size_t)bc * 64 + kw;
    short8v* yt = (short8v*)Yt;
    const size_t PL8 = (size_t)32 * 32768;    // plane stride in short8 units
#pragma unroll
    for (int grp = 0; grp < 2; ++grp) {
        short8v vrh, vrl, vih, vil;
#pragma unroll
        for (int j = 0; j < 8; ++j) {
            float vr = ar[grp * 8 + j], vi = ai[grp * 8 + j];
            unsigned short h1 = f2bf(vr);
            vrh[j] = (short)h1; vrl[j] = (short)f2bf(vr - bf2f(h1));
            unsigned short h2 = f2bf(vi);
            vih[j] = (short)h2; vil[j] = (short)f2bf(vi - bf2f(h2));
        }
        size_t gi = (size_t)((hfirst >> 3) + grp) * 32768 + p;
        yt[0 * PL8 + gi] = vrh;
        yt[1 * PL8 + gi] = vrl;
        yt[2 * PL8 + gi] = vih;
        yt[3 * PL8 + gi] = vil;
    }
}

// Split-bf16 complex MFMA GEMM: Out[r][p] = sum_s T[r][s] * D[s][p], r in [0,R), R = RT_W*64.
// AF: prefragged T (6 planes); Bt: data planes [pl][S/8][32768][8] bf16.
// Block: 4 M-stacked waves (full R), N = 64 (4 ptile iterations), B tile staged in LDS.
template<int S, int RT_W>
__global__ __launch_bounds__(256) void k_cmfma(const unsigned short* __restrict__ AF,
                                               const unsigned short* __restrict__ Bt,
                                               float2* __restrict__ Out) {
    constexpr int KC = S / 32;
    constexpr int SG = S / 8;
    constexpr int RTOT = RT_W * 4;
    __shared__ __align__(16) unsigned short bs[4 * SG * 16 * 8];
    int t = threadIdx.x;
    int wave = t >> 6, lane = t & 63;
    int rt0 = wave * RT_W;
    int colp = lane & 15, rowq = lane >> 4;
    const short8v* AFv = (const short8v*)AF;
    const short8v* bsv = (const short8v*)bs;
    const size_t PLA = (size_t)KC * RTOT * 64;     // A plane stride (short8 units)

    for (int pt = 0; pt < 4; ++pt) {
        int p0 = blockIdx.x * 64 + pt * 16;
        __syncthreads();
        {   // stage B tile: 4 planes x SG groups x 16 p x 16B
            const float4* src = (const float4*)Bt;
            float4* dst = (float4*)bs;
            for (int e = t; e < 4 * SG * 16; e += 256) {
                int pl = e / (SG * 16); int rem = e - pl * (SG * 16);
                int g = rem >> 4, li = rem & 15;
                dst[e] = src[((size_t)pl * SG + g) * 32768 + p0 + li];
            }
        }
        __syncthreads();
        float4v accR[RT_W], accI[RT_W];
#pragma unroll
        for (int rt = 0; rt < RT_W; ++rt) {
            accR[rt] = (float4v){0.f, 0.f, 0.f, 0.f};
            accI[rt] = (float4v){0.f, 0.f, 0.f, 0.f};
        }
#pragma unroll
        for (int kc = 0; kc < KC; ++kc) {
            int gi = kc * 4 + rowq;
            short8v Brh = bsv[((0 * SG + gi) << 4) + colp];
            short8v Brl = bsv[((1 * SG + gi) << 4) + colp];
            short8v Bih = bsv[((2 * SG + gi) << 4) + colp];
            short8v Bil = bsv[((3 * SG + gi) << 4) + colp];
#pragma unroll
            for (int rt = 0; rt < RT_W; ++rt) {
                size_t ab = ((size_t)kc * RTOT + rt0 + rt) * 64 + lane;
                short8v A0 = AFv[0 * PLA + ab];   // Trh
                short8v A1 = AFv[1 * PLA + ab];   // Trl
                short8v A2 = AFv[2 * PLA + ab];   // Tih
                short8v A3 = AFv[3 * PLA + ab];   // Til
                short8v A4 = AFv[4 * PLA + ab];   // -Tih
                short8v A5 = AFv[5 * PLA + ab];   // -Til
                float4v r_ = accR[rt];
                r_ = __builtin_amdgcn_mfma_f32_16x16x32_bf16(A0, Brh, r_, 0, 0, 0);
                r_ = __builtin_amdgcn_mfma_f32_16x16x32_bf16(A0, Brl, r_, 0, 0, 0);
                r_ = __builtin_amdgcn_mfma_f32_16x16x32_bf16(A1, Brh, r_, 0, 0, 0);
                r_ = __builtin_amdgcn_mfma_f32_16x16x32_bf16(A4, Bih, r_, 0, 0, 0);
                r_ = __builtin_amdgcn_mfma_f32_16x16x32_bf16(A4, Bil, r_, 0, 0, 0);
                r_ = __builtin_amdgcn_mfma_f32_16x16x32_bf16(A5, Bih, r_, 0, 0, 0);
                accR[rt] = r_;
                float4v i_ = accI[rt];
                i_ = __builtin_amdgcn_mfma_f32_16x16x32_bf16(A2, Brh, i_, 0, 0, 0);
                i_ = __builtin_amdgcn_mfma_f32_16x16x32_bf16(A2, Brl, i_, 0, 0, 0);
                i_ = __builtin_amdgcn_mfma_f32_16x16x32_bf16(A3, Brh, i_, 0, 0, 0);
                i_ = __builtin_amdgcn_mfma_f32_16x16x32_bf16(A0, Bih, i_, 0, 0, 0);
                i_ = __builtin_amdgcn_mfma_f32_16x16x32_bf16(A0, Bil, i_, 0, 0, 0);
                i_ = __builtin_amdgcn_mfma_f32_16x16x32_bf16(A1, Bih, i_, 0, 0, 0);
                accI[rt] = i_;
            }
        }
#pragma unroll
        for (int rt = 0; rt < RT_W; ++rt) {
            int rbase = (rt0 + rt) * 16 + rowq * 4;
#pragma unroll
            for (int q = 0; q < 4; ++q)
                Out[(size_t)(rbase + q) * P_ + p0 + colp] = make_float2(accR[rt][q], accI[rt][q]);
        }
    }
}

// MFMA contract (unchanged from round 4).
__global__ __launch_bounds__(256) void k_contract(const float2* __restrict__ XF,
                                                  const unsigned short* __restrict__ bA,
                                                  const unsigned short* __restrict__ gB,
                                                  const float* __restrict__ a1, const float* __restrict__ a2,
                                                  float2* __restrict__ OF) {
    __shared__ __align__(16) float2 ts[64 * 66];
    int t = threadIdx.x;
    int k = blockIdx.x >> 2;
    int ytile = blockIdx.x & 3;
    int y0 = ytile << 4;
    int reg = (k >= 64) ? 1 : 0;
    int x = k & 63;
    int itile = t >> 6, lane = t & 63;
    int ylane = lane & 15, qg = lane >> 4;

    const short8v* gBv = (const short8v*)gB;
    short8v g_r  = gBv[(((size_t)(0 * 2 + reg) * 64 + x) * 4 + ytile) * 64 + lane];
    short8v g_i  = gBv[(((size_t)(1 * 2 + reg) * 64 + x) * 4 + ytile) * 64 + lane];
    short8v g_ni = gBv[(((size_t)(2 * 2 + reg) * 64 + x) * 4 + ytile) * 64 + lane];

    const short8v* bAv = (const short8v*)bA;
    size_t aR = (((size_t)(0 * 2 + reg) * 4 + itile) * 128) * 64 + lane;
    size_t aI = (((size_t)(1 * 2 + reg) * 4 + itile) * 128) * 64 + lane;

    const float2* xfp = XF + (size_t)k * 32768 + y0 + ylane;

    float tr[4][4], ti[4][4];
#pragma unroll
    for (int q = 0; q < 4; ++q)
#pragma unroll
        for (int b = 0; b < 4; ++b) { tr[q][b] = 0.f; ti[q][b] = 0.f; }

#pragma unroll 2
    for (int c = 0; c < 128; ++c) {
        short8v av = bAv[aR + (size_t)c * 64];
        short8v aw = bAv[aI + (size_t)c * 64];
        float4v z4 = {0.f, 0.f, 0.f, 0.f};
        float4v wr = __builtin_amdgcn_mfma_f32_16x16x32_bf16(av, g_r, z4, 0, 0, 0);
        wr = __builtin_amdgcn_mfma_f32_16x16x32_bf16(aw, g_ni, wr, 0, 0, 0);
        float4v wi = __builtin_amdgcn_mfma_f32_16x16x32_bf16(av, g_i, z4, 0, 0, 0);
        wi = __builtin_amdgcn_mfma_f32_16x16x32_bf16(aw, g_r, wi, 0, 0, 0);
#pragma unroll
        for (int b = 0; b < 4; ++b) {
            float2 xv = xfp[(size_t)b * 8192 + (size_t)c * 64];
#pragma unroll
            for (int q = 0; q < 4; ++q) {
                tr[q][b] = fmaf(wr[q], xv.x, fmaf(-wi[q], xv.y, tr[q][b]));
                ti[q][b] = fmaf(wr[q], xv.y, fmaf( wi[q], xv.x, ti[q][b]));
            }
        }
    }

#pragma unroll
    for (int q = 0; q < 4; ++q) {
        int i = itile * 16 + qg * 4 + q;
#pragma unroll
        for (int b = 0; b < 4; ++b)
            ts[i * 66 + b * 16 + ylane] = make_float2(tr[q][b], ti[q][b]);
    }
    __syncthreads();

    int o = t >> 1, m0 = (t & 1) * 8;
    const float* ap = reg ? a2 : a1;
    const float2* ap2 = (const float2*)ap;
    float er[4][8], ei[4][8];
#pragma unroll
    for (int bb = 0; bb < 4; ++bb)
#pragma unroll
        for (int mm = 0; mm < 8; ++mm) { er[bb][mm] = 0.f; ei[bb][mm] = 0.f; }
    for (int ii = 0; ii < 64; ++ii) {
        float2 a = ap2[o * 64 + ii];
#pragma unroll
        for (int bb = 0; bb < 4; ++bb) {
            const float2* tp = &ts[ii * 66 + bb * 16 + m0];
#pragma unroll
            for (int mm = 0; mm < 8; ++mm) {
                float2 tv = tp[mm];
                er[bb][mm] = fmaf(a.x, tv.x, fmaf(-a.y, tv.y, er[bb][mm]));
                ei[bb][mm] = fmaf(a.x, tv.y, fmaf( a.y, tv.x, ei[bb][mm]));
            }
        }
    }
#pragma unroll
    for (int bb = 0; bb < 4; ++bb)
#pragma unroll
        for (int mm = 0; mm < 8; ++mm)
            OF[(((size_t)k * 4 + bb) * 128 + o) * 64 + y0 + m0 + mm] = make_float2(er[bb][mm], ei[bb][mm]);
}

// OF fp32 [k][p] -> OFt 4 bf16 planes [k>>3][p][k&7]
__global__ __launch_bounds__(256) void k_repack(const float2* __restrict__ OF,
                                                unsigned short* __restrict__ OFt) {
    int t = threadIdx.x;
    size_t p = (size_t)blockIdx.x * 256 + t;
    int kg = blockIdx.y;
    short8v vrh, vrl, vih, vil;
#pragma unroll
    for (int j = 0; j < 8; ++j) {
        float2 v = OF[(size_t)(kg * 8 + j) * P_ + p];
        unsigned short h1 = f2bf(v.x);
        vrh[j] = (short)h1; vrl[j] = (short)f2bf(v.x - bf2f(h1));
        unsigned short h2 = f2bf(v.y);
        vih[j] = (short)h2; vil[j] = (short)f2bf(v.y - bf2f(h2));
    }
    short8v* dst = (short8v*)OFt;
    const size_t PL8 = (size_t)16 * 32768;
    size_t gi = (size_t)kg * 32768 + p;
    dst[0 * PL8 + gi] = vrh;
    dst[1 * PL8 + gi] = vrl;
    dst[2 * PL8 + gi] = vih;
    dst[3 * PL8 + gi] = vil;
}

// out[b,o,h,w'] from Z[h][b][o][kw] using radix-4 symmetry over w.
__global__ __launch_bounds__(256) void k_invW(const float2* __restrict__ Z,
                                              const float2* __restrict__ IW,
                                              float* __restrict__ out) {
    __shared__ __align__(16) float2 zs[16][64];
    int t = threadIdx.x;
    int w = t & 63, rs = t >> 6;
    size_t row0 = (size_t)blockIdx.x * 16;
    {
        const float4* src = (const float4*)(Z + row0 * 64);
        float4* dst = (float4*)zs;
        dst[t] = src[t];
        dst[t + 256] = src[t + 256];
    }
    __syncthreads();

    float sr[4][4], si[4][4];
#pragma unroll
    for (int pp = 0; pp < 4; ++pp)
#pragma unroll
        for (int m = 0; m < 4; ++m) { sr[pp][m] = 0.f; si[pp][m] = 0.f; }

#pragma unroll
    for (int kwh = 0; kwh < 2; ++kwh) {
        float2 IWr[32];
#pragma unroll
        for (int q = 0; q < 32; ++q) IWr[q] = IW[(kwh * 32 + q) * 64 + w];
#pragma unroll
        for (int pass = 0; pass < 4; ++pass) {
            int r = rs * 4 + pass;
            const float4* zrow = (const float4*)&zs[r][kwh * 32];
#pragma unroll
            for (int q = 0; q < 16; ++q) {
                float4 zq = zrow[q];
                float2 f0 = IWr[2 * q], f1 = IWr[2 * q + 1];
                if ((q & 1) == 0) {
                    sr[pass][0] = fmaf(zq.x, f0.x, fmaf(-zq.y, f0.y, sr[pass][0]));
                    si[pass][0] = fmaf(zq.x, f0.y, fmaf( zq.y, f0.x, si[pass][0]));
                    sr[pass][1] = fmaf(zq.z, f1.x, fmaf(-zq.w, f1.y, sr[pass][1]));
                    si[pass][1] = fmaf(zq.z, f1.y, fmaf( zq.w, f1.x, si[pass][1]));
                } else {
                    sr[pass][2] = fmaf(zq.x, f0.x, fmaf(-zq.y, f0.y, sr[pass][2]));
                    si[pass][2] = fmaf(zq.x, f0.y, fmaf( zq.y, f0.x, si[pass][2]));
                    sr[pass][3] = fmaf(zq.z, f1.x, fmaf(-zq.w, f1.y, sr[pass][3]));
                    si[pass][3] = fmaf(zq.z, f1.y, fmaf( zq.w, f1.x, si[pass][3]));
                }
            }
        }
    }

#pragma unroll
    for (int pass = 0; pass < 4; ++pass) {
        int r = rs * 4 + pass;
        size_t row = row0 + r;
        int h = (int)(row >> 9);
        int rem = (int)(row & 511);
        int b = rem >> 7, o = rem & 127;
        float s0r = sr[pass][0], s1r = sr[pass][1], s2r = sr[pass][2], s3r = sr[pass][3];
        float s1i = si[pass][1], s3i = si[pass][3];
        float o0 = s0r + s1r + s2r + s3r;
        float o1 = s0r - s1i - s2r + s3i;
        float o2 = s0r - s1r + s2r - s3r;
        float o3 = s0r + s1i - s2r - s3i;
        size_t base = (((size_t)(b * 128 + o)) * 256 + h) * 256 + w;
        out[base + 0]   = o0;
        out[base + 64]  = o1;
        out[base + 128] = o2;
        out[base + 192] = o3;
    }
}

extern "C" void kernel_launch(void* const* d_in, const int* in_sizes, int n_in,
                              void* d_out, int out_size, void* d_ws, size_t ws_size,
                              hipStream_t stream) {
    const float* x  = (const float*)d_in[0];
    const float* a1 = (const float*)d_in[1];
    const float* b1 = (const float*)d_in[2];
    const float* c1 = (const float*)d_in[3];
    const float* d1 = (const float*)d_in[4];
    const float* a2 = (const float*)d_in[5];
    const float* b2 = (const float*)d_in[6];
    const float* c2 = (const float*)d_in[7];
    const float* d2 = (const float*)d_in[8];
    float* out = (float*)d_out;
    float* wsf = (float*)d_ws;

    if (ws_size < WS_FLOATS * sizeof(float)) return;

    unsigned short* Yt  = (unsigned short*)(wsf + oYT);
    float2*         Zb  = (float2*)(wsf + oYT);          // Z aliases Yt region (after contract)
    float2*         XF  = (float2*)(wsf + oXF);
    unsigned short* OFt = (unsigned short*)(wsf + oXF);  // OFt aliases XF (after contract)
    float2*         OF  = (float2*)(wsf + oOF);
    float2*         FW  = (float2*)(wsf + oFW);
    float2*         IW  = (float2*)(wsf + oIW);
    float2*         G   = (float2*)(wsf + oG);
    unsigned short* AF1 = (unsigned short*)(wsf + oAF1);
    unsigned short* AF2 = (unsigned short*)(wsf + oAF2);
    unsigned short* bA  = (unsigned short*)(wsf + oYT);  // after cgemm1, Yt region is dead
    unsigned short* gB  = bA + 1048576;

    k_twiddle<<<80, 256, 0, stream>>>(wsf);
    k_prepT<<<1536, 256, 0, stream>>>(AF1, AF2);
    k_g<<<1024, 256, 0, stream>>>(c1, d1, c2, d2, G);
    k_stage1<<<2048, 256, 0, stream>>>(x, FW, Yt);
    k_cmfma<256, 2><<<512, 256, 0, stream>>>(AF1, Yt, XF);
    k_prepBG<<<7168, 256, 0, stream>>>(b1, b2, G, bA, gB);
    k_contract<<<512, 256, 0, stream>>>(XF, bA, gB, a1, a2, OF);
    k_repack<<<dim3(128, 16), 256, 0, stream>>>(OF, OFt);
    k_cmfma<128, 4><<<512, 256, 0, stream>>>(AF2, OFt, Zb);
    k_invW<<<8192, 256, 0, stream>>>(Zb, IW, out);

    (void)in_sizes; (void)n_in; (void)out_size;
}

// Round 6
// 344.789 us; speedup vs baseline: 5.1338x; 1.1930x over previous
//
#include <hip/hip_runtime.h>
#include <math.h>

// FactorizedSpectralConv2d: pruned-DFT + TT contraction, MFMA everywhere matmul-shaped.
//
//   k_twiddle : IW (invW) fp32 twiddle table
//   k_prepT   : split-bf16 MFMA A-frag tables for FH / IH DFT matrices + B-frag table for FW
//   k_g       : g[r][j][x][y] = sum_k cc[j,x,k]*dc[k,y]
//   k_stage1m : W-DFT of x via split-bf16 MFMA -> Yt 4 bf16 planes [h/8][p][8] (hi/lo re/im)
//   k_cmfma   : XF[k][p] = sum_h FH[k][h] Yt[h][p]    (split-bf16 complex MFMA)
//   k_prepBG  : bf16 frag tables for b (A) and g (B) of the TT contraction
//   k_contract: MFMA w-GEMM + fp32 t-update + a-epilogue  -> OF fp32
//   k_repack  : OF fp32 -> OFt 4 bf16 planes [k/8][p][8]
//   k_cmfma   : Z[h][q] = sum_k IH[h][k] OFt[k][q]
//   k_invW    : out = radix-4 inverse W-DFT of Z (scales folded into IW)

#define TWO_PI 6.28318530717958647692f

typedef __attribute__((ext_vector_type(8))) short short8v;   // 8 bf16 (4 VGPRs)
typedef __attribute__((ext_vector_type(4))) float float4v;   // MFMA C/D

namespace {
constexpr size_t P_ = 32768;            // B*C*KW pixel batch width

// workspace float offsets
constexpr size_t oYT = 0;                     // Yt: 4 planes [32][32768][8] bf16 = 16.77M floats
                                              //   then bA/gB (prepBG), then Z f2 (cgemm2/invW)
constexpr size_t oXF = 16777216;              // XF f2 33.5MB; later OFt 4 planes [16][32768][8]
constexpr size_t oOF = 25165824;              // OF f2 33.5MB
constexpr size_t oBF = 33554432;              // FW B-frag table: 65536 shorts = 32768 floats
constexpr size_t oAF1 = 33587200;             // FH frags: 196608 shorts = 98304 floats
constexpr size_t oAF2 = 33685504;             // IH frags: 98304 floats
constexpr size_t oIW = 33783808;              // [64][64] f2
constexpr size_t oG  = 33792000;              // [2][32][64][64] f2
constexpr size_t WS_FLOATS = oG + 524288;     // ~137.3 MB
}

__device__ __forceinline__ unsigned short f2bf(float f) {   // RNE float->bf16 bits
    unsigned int u = __float_as_uint(f);
    unsigned int r = (u + 0x7FFFu + ((u >> 16) & 1u)) >> 16;
    return (unsigned short)r;
}
__device__ __forceinline__ float bf2f(unsigned short b) {
    return __uint_as_float(((unsigned int)b) << 16);
}

__global__ __launch_bounds__(256) void k_twiddle(float* __restrict__ wsf) {
    int idx = blockIdx.x * 256 + threadIdx.x;
    if (idx < 4096) {                        // IW[kw][w<64], scale s_kw/65536
        int kw = idx >> 6, w = idx & 63;
        int ph = (kw * w) & 255;
        float ang = TWO_PI * (float)ph / 256.0f;
        float s, c; sincosf(ang, &s, &c);
        float sc = ((kw == 0) ? 1.0f : 2.0f) / 65536.0f;
        ((float2*)(wsf + oIW))[idx] = make_float2(sc * c, sc * s);
    }
}

// Split-bf16 fragment tables for the DFT matrices.
// AF layout: AF[pl][kc][rt][lane][e], pl: 0 Trh 1 Trl 2 Tih 3 Til 4 -Tih 5 -Til.
// AF1 = FH (R=128 kept kh rows, S=256 h), AF2 = IH (R=256 h rows, S=128 k).
// BF = FW B-frags [pl(4: ch,cl,sh,sl)][kc(8)][nt(4)][lane][e]; col=kw, k=w.
__global__ __launch_bounds__(256) void k_prepT(unsigned short* __restrict__ AF1,
                                               unsigned short* __restrict__ AF2,
                                               unsigned short* __restrict__ BF) {
    int idx = blockIdx.x * 256 + threadIdx.x;      // < 458752
    if (idx < 393216) {
        int tbl = (idx >= 196608);
        int id = tbl ? (idx - 196608) : idx;
        int e = id & 7, lane = (id >> 3) & 63;
        int pl = id >> 15;
        float ang;
        if (!tbl) {
            int rt = (id >> 9) & 7, kc = (id >> 12) & 7;
            int r = rt * 16 + (lane & 15);             // k-row (128)
            int s = kc * 32 + 8 * (lane >> 4) + e;     // h (256)
            int kh = r + ((r >= 64) ? 128 : 0);
            int ph = (kh * s) & 255;
            ang = -TWO_PI * (float)ph / 256.0f;
        } else {
            int rt = (id >> 9) & 15, kc = (id >> 13) & 3;
            int r = rt * 16 + (lane & 15);             // h (256)
            int s = kc * 32 + 8 * (lane >> 4) + e;     // k (128)
            int kh = s + ((s >= 64) ? 128 : 0);
            int ph = (kh * r) & 255;
            ang = TWO_PI * (float)ph / 256.0f;
        }
        float sn, cs; sincosf(ang, &sn, &cs);
        float base = (pl < 2) ? cs : ((pl < 4) ? sn : -sn);
        unsigned short hi = f2bf(base);
        unsigned short out = (pl & 1) ? f2bf(base - bf2f(hi)) : hi;
        (tbl ? AF2 : AF1)[id] = out;
    } else {
        int id = idx - 393216;                          // < 65536
        int e = id & 7, lane = (id >> 3) & 63;
        int nt = (id >> 9) & 3, kc = (id >> 11) & 7;
        int pl = id >> 14;                              // 0..3
        int kw = nt * 16 + (lane & 15);
        int w = kc * 32 + 8 * (lane >> 4) + e;
        int ph = (w * kw) & 255;
        float ang = -TWO_PI * (float)ph / 256.0f;
        float sn, cs; sincosf(ang, &sn, &cs);
        float base = (pl < 2) ? cs : sn;
        unsigned short hi = f2bf(base);
        unsigned short out = (pl & 1) ? f2bf(base - bf2f(hi)) : hi;
        BF[id] = out;
    }
}

// g[r][j][x][y] = sum_k cc[j,x,k] * dc[k,y]
__global__ __launch_bounds__(256) void k_g(const float* __restrict__ c1, const float* __restrict__ d1,
                                           const float* __restrict__ c2, const float* __restrict__ d2,
                                           float2* __restrict__ G) {
    int idx = blockIdx.x * 256 + threadIdx.x;      // < 262144
    int r = idx >> 17;
    int rem = idx & 131071;
    int j = rem >> 12;
    int xy = rem & 4095;
    int xm = xy >> 6, ym = xy & 63;
    const float* cp = r ? c2 : c1;
    const float* dp = r ? d2 : d1;
    float sr = 0.f, si = 0.f;
    for (int kk = 0; kk < 32; ++kk) {
        float cr = cp[((j * 64 + xm) * 32 + kk) * 2 + 0];
        float ci = cp[((j * 64 + xm) * 32 + kk) * 2 + 1];
        float dr = dp[(kk * 64 + ym) * 2 + 0];
        float di = dp[(kk * 64 + ym) * 2 + 1];
        sr = fmaf(cr, dr, fmaf(-ci, di, sr));
        si = fmaf(cr, di, fmaf( ci, dr, si));
    }
    G[(size_t)(r * 32 + j) * 4096 + xy] = make_float2(sr, si);
}

// bf16 fragment tables for the contraction:
//  bA[plane(r,i)][reg][itile][c][lane][e], gB[plane(r,i,-i)][reg][x][ytile][lane][e]
__global__ __launch_bounds__(256) void k_prepBG(const float* __restrict__ b1, const float* __restrict__ b2,
                                                const float2* __restrict__ G,
                                                unsigned short* __restrict__ bA,
                                                unsigned short* __restrict__ gB) {
    size_t idx = (size_t)blockIdx.x * 256 + threadIdx.x;
    if (idx < 1048576) {
        int e     = idx & 7;
        int lane  = (idx >> 3) & 63;
        int c     = (idx >> 9) & 127;
        int itile = (idx >> 16) & 3;
        int reg   = (idx >> 18) & 1;
        int plane = (idx >> 19) & 1;
        int i = itile * 16 + (lane & 15);
        int j = 8 * (lane >> 4) + e;
        const float* bp = reg ? b2 : b1;
        float v = bp[((size_t)(i * 128 + c) * 32 + j) * 2 + plane];
        bA[idx] = f2bf(v);
    } else if (idx < 1048576 + 786432) {
        size_t i2 = idx - 1048576;
        int e     = i2 & 7;
        int lane  = (i2 >> 3) & 63;
        int ytile = (i2 >> 9) & 3;
        int x     = (i2 >> 11) & 63;
        int reg   = (i2 >> 17) & 1;
        int plane = (int)(i2 >> 18);           // 0,1,2
        int y = ytile * 16 + (lane & 15);
        int j = 8 * (lane >> 4) + e;
        float2 gv = G[(size_t)(reg * 32 + j) * 4096 + x * 64 + y];
        float v = (plane == 0) ? gv.x : ((plane == 1) ? gv.y : -gv.y);
        gB[i2] = f2bf(v);
    }
}

// MFMA W-DFT: block = 128 x-rows (4 waves x 2 mtiles) x 64 kw; K=256 (w), split-bf16.
// x converted hi/lo on the fly; FW B-frags from BF table (L2-resident).
__global__ __launch_bounds__(256) void k_stage1m(const float* __restrict__ x,
                                                 const unsigned short* __restrict__ BF,
                                                 unsigned short* __restrict__ Yt) {
    int t = threadIdx.x;
    int wave = t >> 6, lane = t & 63;
    size_t row0 = (size_t)blockIdx.x * 128 + (size_t)wave * 32;
    int colp = lane & 15, rowq = lane >> 4;
    const short8v* BFv = (const short8v*)BF;
    const size_t PLB = 8 * 4 * 64;                 // BF plane stride (short8 units)

    float4v accR[2][4], accI[2][4];
#pragma unroll
    for (int rt = 0; rt < 2; ++rt)
#pragma unroll
        for (int nt = 0; nt < 4; ++nt) {
            accR[rt][nt] = (float4v){0.f, 0.f, 0.f, 0.f};
            accI[rt][nt] = (float4v){0.f, 0.f, 0.f, 0.f};
        }

    for (int kc = 0; kc < 8; ++kc) {
        short8v Bch[4], Bcl[4], Bsh[4], Bsl[4];
#pragma unroll
        for (int nt = 0; nt < 4; ++nt) {
            size_t bb = ((size_t)kc * 4 + nt) * 64 + lane;
            Bch[nt] = BFv[0 * PLB + bb];
            Bcl[nt] = BFv[1 * PLB + bb];
            Bsh[nt] = BFv[2 * PLB + bb];
            Bsl[nt] = BFv[3 * PLB + bb];
        }
#pragma unroll
        for (int rt = 0; rt < 2; ++rt) {
            const float* xp = x + (row0 + rt * 16 + colp) * 256 + kc * 32 + 8 * rowq;
            float4 v0 = *(const float4*)xp;
            float4 v1 = *(const float4*)(xp + 4);
            float vv[8] = {v0.x, v0.y, v0.z, v0.w, v1.x, v1.y, v1.z, v1.w};
            short8v xh, xl;
#pragma unroll
            for (int j = 0; j < 8; ++j) {
                unsigned short h = f2bf(vv[j]);
                xh[j] = (short)h;
                xl[j] = (short)f2bf(vv[j] - bf2f(h));
            }
#pragma unroll
            for (int nt = 0; nt < 4; ++nt) {
                float4v r_ = accR[rt][nt];
                r_ = __builtin_amdgcn_mfma_f32_16x16x32_bf16(xh, Bch[nt], r_, 0, 0, 0);
                r_ = __builtin_amdgcn_mfma_f32_16x16x32_bf16(xh, Bcl[nt], r_, 0, 0, 0);
                r_ = __builtin_amdgcn_mfma_f32_16x16x32_bf16(xl, Bch[nt], r_, 0, 0, 0);
                accR[rt][nt] = r_;
                float4v i_ = accI[rt][nt];
                i_ = __builtin_amdgcn_mfma_f32_16x16x32_bf16(xh, Bsh[nt], i_, 0, 0, 0);
                i_ = __builtin_amdgcn_mfma_f32_16x16x32_bf16(xh, Bsl[nt], i_, 0, 0, 0);
                i_ = __builtin_amdgcn_mfma_f32_16x16x32_bf16(xl, Bsh[nt], i_, 0, 0, 0);
                accI[rt][nt] = i_;
            }
        }
    }

    // write split-bf16 Yt: D row=(lane>>4)*4+q -> x-row (h), col=lane&15 -> kw
    short* Yts = (short*)Yt;
    const size_t PLY = (size_t)32 * 32768 * 8;     // plane stride in shorts
#pragma unroll
    for (int rt = 0; rt < 2; ++rt) {
        size_t xrow = row0 + rt * 16 + rowq * 4;   // rows q=0..3
        int h = (int)(xrow & 255), bc = (int)(xrow >> 8);
        size_t gbase = (size_t)(h >> 3) * 32768;
        int e0 = h & 7;                             // 0 or 4
#pragma unroll
        for (int nt = 0; nt < 4; ++nt) {
            size_t p = (size_t)bc * 64 + nt * 16 + colp;
            size_t off = (gbase + p) * 8 + e0;
            float4v R = accR[rt][nt], I = accI[rt][nt];
            short rh[4], rl[4], ih[4], il[4];
#pragma unroll
            for (int q = 0; q < 4; ++q) {
                unsigned short h1 = f2bf(R[q]);
                rh[q] = (short)h1; rl[q] = (short)f2bf(R[q] - bf2f(h1));
                unsigned short h2 = f2bf(I[q]);
                ih[q] = (short)h2; il[q] = (short)f2bf(I[q] - bf2f(h2));
            }
            *(short4*)&Yts[0 * PLY + off] = make_short4(rh[0], rh[1], rh[2], rh[3]);
            *(short4*)&Yts[1 * PLY + off] = make_short4(rl[0], rl[1], rl[2], rl[3]);
            *(short4*)&Yts[2 * PLY + off] = make_short4(ih[0], ih[1], ih[2], ih[3]);
            *(short4*)&Yts[3 * PLY + off] = make_short4(il[0], il[1], il[2], il[3]);
        }
    }
}

// Split-bf16 complex MFMA GEMM: Out[r][p] = sum_s T[r][s] * D[s][p], r in [0,R), R = RT_W*64.
template<int S, int RT_W>
__global__ __launch_bounds__(256) void k_cmfma(const unsigned short* __restrict__ AF,
                                               const unsigned short* __restrict__ Bt,
                                               float2* __restrict__ Out) {
    constexpr int KC = S / 32;
    constexpr int SG = S / 8;
    constexpr int RTOT = RT_W * 4;
    __shared__ __align__(16) unsigned short bs[4 * SG * 16 * 8];
    int t = threadIdx.x;
    int wave = t >> 6, lane = t & 63;
    int rt0 = wave * RT_W;
    int colp = lane & 15, rowq = lane >> 4;
    const short8v* AFv = (const short8v*)AF;
    const short8v* bsv = (const short8v*)bs;
    const size_t PLA = (size_t)KC * RTOT * 64;     // A plane stride (short8 units)

    for (int pt = 0; pt < 4; ++pt) {
        int p0 = blockIdx.x * 64 + pt * 16;
        __syncthreads();
        {   // stage B tile: 4 planes x SG groups x 16 p x 16B
            const float4* src = (const float4*)Bt;
            float4* dst = (float4*)bs;
            for (int e = t; e < 4 * SG * 16; e += 256) {
                int pl = e / (SG * 16); int rem = e - pl * (SG * 16);
                int g = rem >> 4, li = rem & 15;
                dst[e] = src[((size_t)pl * SG + g) * 32768 + p0 + li];
            }
        }
        __syncthreads();
        float4v accR[RT_W], accI[RT_W];
#pragma unroll
        for (int rt = 0; rt < RT_W; ++rt) {
            accR[rt] = (float4v){0.f, 0.f, 0.f, 0.f};
            accI[rt] = (float4v){0.f, 0.f, 0.f, 0.f};
        }
#pragma unroll
        for (int kc = 0; kc < KC; ++kc) {
            int gi = kc * 4 + rowq;
            short8v Brh = bsv[((0 * SG + gi) << 4) + colp];
            short8v Brl = bsv[((1 * SG + gi) << 4) + colp];
            short8v Bih = bsv[((2 * SG + gi) << 4) + colp];
            short8v Bil = bsv[((3 * SG + gi) << 4) + colp];
#pragma unroll
            for (int rt = 0; rt < RT_W; ++rt) {
                size_t ab = ((size_t)kc * RTOT + rt0 + rt) * 64 + lane;
                short8v A0 = AFv[0 * PLA + ab];   // Trh
                short8v A1 = AFv[1 * PLA + ab];   // Trl
                short8v A2 = AFv[2 * PLA + ab];   // Tih
                short8v A3 = AFv[3 * PLA + ab];   // Til
                short8v A4 = AFv[4 * PLA + ab];   // -Tih
                short8v A5 = AFv[5 * PLA + ab];   // -Til
                float4v r_ = accR[rt];
                r_ = __builtin_amdgcn_mfma_f32_16x16x32_bf16(A0, Brh, r_, 0, 0, 0);
                r_ = __builtin_amdgcn_mfma_f32_16x16x32_bf16(A0, Brl, r_, 0, 0, 0);
                r_ = __builtin_amdgcn_mfma_f32_16x16x32_bf16(A1, Brh, r_, 0, 0, 0);
                r_ = __builtin_amdgcn_mfma_f32_16x16x32_bf16(A4, Bih, r_, 0, 0, 0);
                r_ = __builtin_amdgcn_mfma_f32_16x16x32_bf16(A4, Bil, r_, 0, 0, 0);
                r_ = __builtin_amdgcn_mfma_f32_16x16x32_bf16(A5, Bih, r_, 0, 0, 0);
                accR[rt] = r_;
                float4v i_ = accI[rt];
                i_ = __builtin_amdgcn_mfma_f32_16x16x32_bf16(A2, Brh, i_, 0, 0, 0);
                i_ = __builtin_amdgcn_mfma_f32_16x16x32_bf16(A2, Brl, i_, 0, 0, 0);
                i_ = __builtin_amdgcn_mfma_f32_16x16x32_bf16(A3, Brh, i_, 0, 0, 0);
                i_ = __builtin_amdgcn_mfma_f32_16x16x32_bf16(A0, Bih, i_, 0, 0, 0);
                i_ = __builtin_amdgcn_mfma_f32_16x16x32_bf16(A0, Bil, i_, 0, 0, 0);
                i_ = __builtin_amdgcn_mfma_f32_16x16x32_bf16(A1, Bih, i_, 0, 0, 0);
                accI[rt] = i_;
            }
        }
#pragma unroll
        for (int rt = 0; rt < RT_W; ++rt) {
            int rbase = (rt0 + rt) * 16 + rowq * 4;
#pragma unroll
            for (int q = 0; q < 4; ++q)
                Out[(size_t)(rbase + q) * P_ + p0 + colp] = make_float2(accR[rt][q], accI[rt][q]);
        }
    }
}

// MFMA contract (unchanged).
__global__ __launch_bounds__(256) void k_contract(const float2* __restrict__ XF,
                                                  const unsigned short* __restrict__ bA,
                                                  const unsigned short* __restrict__ gB,
                                                  const float* __restrict__ a1, const float* __restrict__ a2,
                                                  float2* __restrict__ OF) {
    __shared__ __align__(16) float2 ts[64 * 66];
    int t = threadIdx.x;
    int k = blockIdx.x >> 2;
    int ytile = blockIdx.x & 3;
    int y0 = ytile << 4;
    int reg = (k >= 64) ? 1 : 0;
    int x = k & 63;
    int itile = t >> 6, lane = t & 63;
    int ylane = lane & 15, qg = lane >> 4;

    const short8v* gBv = (const short8v*)gB;
    short8v g_r  = gBv[(((size_t)(0 * 2 + reg) * 64 + x) * 4 + ytile) * 64 + lane];
    short8v g_i  = gBv[(((size_t)(1 * 2 + reg) * 64 + x) * 4 + ytile) * 64 + lane];
    short8v g_ni = gBv[(((size_t)(2 * 2 + reg) * 64 + x) * 4 + ytile) * 64 + lane];

    const short8v* bAv = (const short8v*)bA;
    size_t aR = (((size_t)(0 * 2 + reg) * 4 + itile) * 128) * 64 + lane;
    size_t aI = (((size_t)(1 * 2 + reg) * 4 + itile) * 128) * 64 + lane;

    const float2* xfp = XF + (size_t)k * 32768 + y0 + ylane;

    float tr[4][4], ti[4][4];
#pragma unroll
    for (int q = 0; q < 4; ++q)
#pragma unroll
        for (int b = 0; b < 4; ++b) { tr[q][b] = 0.f; ti[q][b] = 0.f; }

#pragma unroll 2
    for (int c = 0; c < 128; ++c) {
        short8v av = bAv[aR + (size_t)c * 64];
        short8v aw = bAv[aI + (size_t)c * 64];
        float4v z4 = {0.f, 0.f, 0.f, 0.f};
        float4v wr = __builtin_amdgcn_mfma_f32_16x16x32_bf16(av, g_r, z4, 0, 0, 0);
        wr = __builtin_amdgcn_mfma_f32_16x16x32_bf16(aw, g_ni, wr, 0, 0, 0);
        float4v wi = __builtin_amdgcn_mfma_f32_16x16x32_bf16(av, g_i, z4, 0, 0, 0);
        wi = __builtin_amdgcn_mfma_f32_16x16x32_bf16(aw, g_r, wi, 0, 0, 0);
#pragma unroll
        for (int b = 0; b < 4; ++b) {
            float2 xv = xfp[(size_t)b * 8192 + (size_t)c * 64];
#pragma unroll
            for (int q = 0; q < 4; ++q) {
                tr[q][b] = fmaf(wr[q], xv.x, fmaf(-wi[q], xv.y, tr[q][b]));
                ti[q][b] = fmaf(wr[q], xv.y, fmaf( wi[q], xv.x, ti[q][b]));
            }
        }
    }

#pragma unroll
    for (int q = 0; q < 4; ++q) {
        int i = itile * 16 + qg * 4 + q;
#pragma unroll
        for (int b = 0; b < 4; ++b)
            ts[i * 66 + b * 16 + ylane] = make_float2(tr[q][b], ti[q][b]);
    }
    __syncthreads();

    int o = t >> 1, m0 = (t & 1) * 8;
    const float* ap = reg ? a2 : a1;
    const float2* ap2 = (const float2*)ap;
    float er[4][8], ei[4][8];
#pragma unroll
    for (int bb = 0; bb < 4; ++bb)
#pragma unroll
        for (int mm = 0; mm < 8; ++mm) { er[bb][mm] = 0.f; ei[bb][mm] = 0.f; }
    for (int ii = 0; ii < 64; ++ii) {
        float2 a = ap2[o * 64 + ii];
#pragma unroll
        for (int bb = 0; bb < 4; ++bb) {
            const float2* tp = &ts[ii * 66 + bb * 16 + m0];
#pragma unroll
            for (int mm = 0; mm < 8; ++mm) {
                float2 tv = tp[mm];
                er[bb][mm] = fmaf(a.x, tv.x, fmaf(-a.y, tv.y, er[bb][mm]));
                ei[bb][mm] = fmaf(a.x, tv.y, fmaf( a.y, tv.x, ei[bb][mm]));
            }
        }
    }
#pragma unroll
    for (int bb = 0; bb < 4; ++bb)
#pragma unroll
        for (int mm = 0; mm < 8; ++mm)
            OF[(((size_t)k * 4 + bb) * 128 + o) * 64 + y0 + m0 + mm] = make_float2(er[bb][mm], ei[bb][mm]);
}

// OF fp32 [k][p] -> OFt 4 bf16 planes [k>>3][p][k&7]
__global__ __launch_bounds__(256) void k_repack(const float2* __restrict__ OF,
                                                unsigned short* __restrict__ OFt) {
    int t = threadIdx.x;
    size_t p = (size_t)blockIdx.x * 256 + t;
    int kg = blockIdx.y;
    short8v vrh, vrl, vih, vil;
#pragma unroll
    for (int j = 0; j < 8; ++j) {
        float2 v = OF[(size_t)(kg * 8 + j) * P_ + p];
        unsigned short h1 = f2bf(v.x);
        vrh[j] = (short)h1; vrl[j] = (short)f2bf(v.x - bf2f(h1));
        unsigned short h2 = f2bf(v.y);
        vih[j] = (short)h2; vil[j] = (short)f2bf(v.y - bf2f(h2));
    }
    short8v* dst = (short8v*)OFt;
    const size_t PL8 = (size_t)16 * 32768;
    size_t gi = (size_t)kg * 32768 + p;
    dst[0 * PL8 + gi] = vrh;
    dst[1 * PL8 + gi] = vrl;
    dst[2 * PL8 + gi] = vih;
    dst[3 * PL8 + gi] = vil;
}

// out[b,o,h,w'] from Z[h][b][o][kw] using radix-4 symmetry over w.
__global__ __launch_bounds__(256) void k_invW(const float2* __restrict__ Z,
                                              const float2* __restrict__ IW,
                                              float* __restrict__ out) {
    __shared__ __align__(16) float2 zs[16][64];
    int t = threadIdx.x;
    int w = t & 63, rs = t >> 6;
    size_t row0 = (size_t)blockIdx.x * 16;
    {
        const float4* src = (const float4*)(Z + row0 * 64);
        float4* dst = (float4*)zs;
        dst[t] = src[t];
        dst[t + 256] = src[t + 256];
    }
    __syncthreads();

    float sr[4][4], si[4][4];
#pragma unroll
    for (int pp = 0; pp < 4; ++pp)
#pragma unroll
        for (int m = 0; m < 4; ++m) { sr[pp][m] = 0.f; si[pp][m] = 0.f; }

#pragma unroll
    for (int kwh = 0; kwh < 2; ++kwh) {
        float2 IWr[32];
#pragma unroll
        for (int q = 0; q < 32; ++q) IWr[q] = IW[(kwh * 32 + q) * 64 + w];
#pragma unroll
        for (int pass = 0; pass < 4; ++pass) {
            int r = rs * 4 + pass;
            const float4* zrow = (const float4*)&zs[r][kwh * 32];
#pragma unroll
            for (int q = 0; q < 16; ++q) {
                float4 zq = zrow[q];
                float2 f0 = IWr[2 * q], f1 = IWr[2 * q + 1];
                if ((q & 1) == 0) {
                    sr[pass][0] = fmaf(zq.x, f0.x, fmaf(-zq.y, f0.y, sr[pass][0]));
                    si[pass][0] = fmaf(zq.x, f0.y, fmaf( zq.y, f0.x, si[pass][0]));
                    sr[pass][1] = fmaf(zq.z, f1.x, fmaf(-zq.w, f1.y, sr[pass][1]));
                    si[pass][1] = fmaf(zq.z, f1.y, fmaf( zq.w, f1.x, si[pass][1]));
                } else {
                    sr[pass][2] = fmaf(zq.x, f0.x, fmaf(-zq.y, f0.y, sr[pass][2]));
                    si[pass][2] = fmaf(zq.x, f0.y, fmaf( zq.y, f0.x, si[pass][2]));
                    sr[pass][3] = fmaf(zq.z, f1.x, fmaf(-zq.w, f1.y, sr[pass][3]));
                    si[pass][3] = fmaf(zq.z, f1.y, fmaf( zq.w, f1.x, si[pass][3]));
                }
            }
        }
    }

#pragma unroll
    for (int pass = 0; pass < 4; ++pass) {
        int r = rs * 4 + pass;
        size_t row = row0 + r;
        int h = (int)(row >> 9);
        int rem = (int)(row & 511);
        int b = rem >> 7, o = rem & 127;
        float s0r = sr[pass][0], s1r = sr[pass][1], s2r = sr[pass][2], s3r = sr[pass][3];
        float s1i = si[pass][1], s3i = si[pass][3];
        float o0 = s0r + s1r + s2r + s3r;
        float o1 = s0r - s1i - s2r + s3i;
        float o2 = s0r - s1r + s2r - s3r;
        float o3 = s0r + s1i - s2r - s3i;
        size_t base = (((size_t)(b * 128 + o)) * 256 + h) * 256 + w;
        out[base + 0]   = o0;
        out[base + 64]  = o1;
        out[base + 128] = o2;
        out[base + 192] = o3;
    }
}

extern "C" void kernel_launch(void* const* d_in, const int* in_sizes, int n_in,
                              void* d_out, int out_size, void* d_ws, size_t ws_size,
                              hipStream_t stream) {
    const float* x  = (const float*)d_in[0];
    const float* a1 = (const float*)d_in[1];
    const float* b1 = (const float*)d_in[2];
    const float* c1 = (const float*)d_in[3];
    const float* d1 = (const float*)d_in[4];
    const float* a2 = (const float*)d_in[5];
    const float* b2 = (const float*)d_in[6];
    const float* c2 = (const float*)d_in[7];
    const float* d2 = (const float*)d_in[8];
    float* out = (float*)d_out;
    float* wsf = (float*)d_ws;

    if (ws_size < WS_FLOATS * sizeof(float)) return;

    unsigned short* Yt  = (unsigned short*)(wsf + oYT);
    float2*         Zb  = (float2*)(wsf + oYT);          // Z aliases Yt region (after contract)
    float2*         XF  = (float2*)(wsf + oXF);
    unsigned short* OFt = (unsigned short*)(wsf + oXF);  // OFt aliases XF (after contract)
    float2*         OF  = (float2*)(wsf + oOF);
    float2*         IW  = (float2*)(wsf + oIW);
    float2*         G   = (float2*)(wsf + oG);
    unsigned short* BF  = (unsigned short*)(wsf + oBF);
    unsigned short* AF1 = (unsigned short*)(wsf + oAF1);
    unsigned short* AF2 = (unsigned short*)(wsf + oAF2);
    unsigned short* bA  = (unsigned short*)(wsf + oYT);  // after cmfma1, Yt region is dead
    unsigned short* gB  = bA + 1048576;

    k_twiddle<<<16, 256, 0, stream>>>(wsf);
    k_prepT<<<1792, 256, 0, stream>>>(AF1, AF2, BF);
    k_g<<<1024, 256, 0, stream>>>(c1, d1, c2, d2, G);
    k_stage1m<<<1024, 256, 0, stream>>>(x, BF, Yt);
    k_cmfma<256, 2><<<512, 256, 0, stream>>>(AF1, Yt, XF);
    k_prepBG<<<7168, 256, 0, stream>>>(b1, b2, G, bA, gB);
    k_contract<<<512, 256, 0, stream>>>(XF, bA, gB, a1, a2, OF);
    k_repack<<<dim3(128, 16), 256, 0, stream>>>(OF, OFt);
    k_cmfma<128, 4><<<512, 256, 0, stream>>>(AF2, OFt, Zb);
    k_invW<<<8192, 256, 0, stream>>>(Zb, IW, out);

    (void)in_sizes; (void)n_in; (void)out_size;
}

// Round 7
// 331.516 us; speedup vs baseline: 5.3394x; 1.0400x over previous
//
#include <hip/hip_runtime.h>
#include <math.h>

// FactorizedSpectralConv2d: pruned-DFT + TT contraction, MFMA everywhere matmul-shaped.
//
//   k_twiddle  : IW (invW) fp32 twiddle table
//   k_prepT    : split-bf16 MFMA A-frag tables for FH / IH DFT matrices + B-frag table for FW
//   k_g        : g[r][j][x][y] = sum_k cc[j,x,k]*dc[k,y]
//   k_stage1m  : W-DFT of x via split-bf16 MFMA -> Yt 4 bf16 planes [h/8][p][8]
//   k_cmfma    : XF[k][p] = sum_h FH[k][h] Yt[h][p]    (split-bf16 complex MFMA)
//   k_prepBG   : bf16 frag tables for b (A) and g (B) of the TT contraction
//   k_prepA    : split-bf16 A-frag table for the a (Cout x r1) epilogue GEMM (over dead G)
//   k_contractA: MFMA w-GEMM + fp32 t-update; t written as split-bf16 frag planes tA
//   k_amfma    : OF[o,(k,b,m)] = sum_i a[o,i] tA[i,(k,b,m)]   (split-bf16 MFMA)
//   k_repack   : OF fp32 -> OFt 4 bf16 planes [k/8][p][8]
//   k_cmfma    : Z[h][q] = sum_k IH[h][k] OFt[k][q]
//   k_invW     : out = radix-4 inverse W-DFT of Z (scales folded into IW)

#define TWO_PI 6.28318530717958647692f

typedef __attribute__((ext_vector_type(8))) short short8v;   // 8 bf16 (4 VGPRs)
typedef __attribute__((ext_vector_type(4))) float float4v;   // MFMA C/D

namespace {
constexpr size_t P_ = 32768;            // B*C*KW pixel batch width

// workspace float offsets
constexpr size_t oYT = 0;                     // Yt: 4 planes [32][32768][8] bf16 = 16.77M floats
                                              //   then bA/gB + tA (contract), then Z f2
constexpr size_t oTA = 1048576;               // tA: 4 planes [8][32768][8] bf16 = 4.19M floats
constexpr size_t oXF = 16777216;              // XF f2 33.5MB; later OFt 4 planes [16][32768][8]
constexpr size_t oOF = 25165824;              // OF f2 33.5MB
constexpr size_t oBF = 33554432;              // FW B-frag table: 65536 shorts = 32768 floats
constexpr size_t oAF1 = 33587200;             // FH frags: 196608 shorts = 98304 floats
constexpr size_t oAF2 = 33685504;             // IH frags: 98304 floats
constexpr size_t oIW = 33783808;              // [64][64] f2
constexpr size_t oG  = 33792000;              // [2][32][64][64] f2 ; AFa overwrites after prepBG
constexpr size_t WS_FLOATS = oG + 524288;     // ~137.3 MB
}

__device__ __forceinline__ unsigned short f2bf(float f) {   // RNE float->bf16 bits
    unsigned int u = __float_as_uint(f);
    unsigned int r = (u + 0x7FFFu + ((u >> 16) & 1u)) >> 16;
    return (unsigned short)r;
}
__device__ __forceinline__ float bf2f(unsigned short b) {
    return __uint_as_float(((unsigned int)b) << 16);
}

__global__ __launch_bounds__(256) void k_twiddle(float* __restrict__ wsf) {
    int idx = blockIdx.x * 256 + threadIdx.x;
    if (idx < 4096) {                        // IW[kw][w<64], scale s_kw/65536
        int kw = idx >> 6, w = idx & 63;
        int ph = (kw * w) & 255;
        float ang = TWO_PI * (float)ph / 256.0f;
        float s, c; sincosf(ang, &s, &c);
        float sc = ((kw == 0) ? 1.0f : 2.0f) / 65536.0f;
        ((float2*)(wsf + oIW))[idx] = make_float2(sc * c, sc * s);
    }
}

// Split-bf16 fragment tables for the DFT matrices (AF1 FH, AF2 IH, BF FW).
__global__ __launch_bounds__(256) void k_prepT(unsigned short* __restrict__ AF1,
                                               unsigned short* __restrict__ AF2,
                                               unsigned short* __restrict__ BF) {
    int idx = blockIdx.x * 256 + threadIdx.x;      // < 458752
    if (idx < 393216) {
        int tbl = (idx >= 196608);
        int id = tbl ? (idx - 196608) : idx;
        int e = id & 7, lane = (id >> 3) & 63;
        int pl = id >> 15;
        float ang;
        if (!tbl) {
            int rt = (id >> 9) & 7, kc = (id >> 12) & 7;
            int r = rt * 16 + (lane & 15);             // k-row (128)
            int s = kc * 32 + 8 * (lane >> 4) + e;     // h (256)
            int kh = r + ((r >= 64) ? 128 : 0);
            int ph = (kh * s) & 255;
            ang = -TWO_PI * (float)ph / 256.0f;
        } else {
            int rt = (id >> 9) & 15, kc = (id >> 13) & 3;
            int r = rt * 16 + (lane & 15);             // h (256)
            int s = kc * 32 + 8 * (lane >> 4) + e;     // k (128)
            int kh = s + ((s >= 64) ? 128 : 0);
            int ph = (kh * r) & 255;
            ang = TWO_PI * (float)ph / 256.0f;
        }
        float sn, cs; sincosf(ang, &sn, &cs);
        float base = (pl < 2) ? cs : ((pl < 4) ? sn : -sn);
        unsigned short hi = f2bf(base);
        unsigned short out = (pl & 1) ? f2bf(base - bf2f(hi)) : hi;
        (tbl ? AF2 : AF1)[id] = out;
    } else {
        int id = idx - 393216;                          // < 65536
        int e = id & 7, lane = (id >> 3) & 63;
        int nt = (id >> 9) & 3, kc = (id >> 11) & 7;
        int pl = id >> 14;                              // 0..3
        int kw = nt * 16 + (lane & 15);
        int w = kc * 32 + 8 * (lane >> 4) + e;
        int ph = (w * kw) & 255;
        float ang = -TWO_PI * (float)ph / 256.0f;
        float sn, cs; sincosf(ang, &sn, &cs);
        float base = (pl < 2) ? cs : sn;
        unsigned short hi = f2bf(base);
        unsigned short out = (pl & 1) ? f2bf(base - bf2f(hi)) : hi;
        BF[id] = out;
    }
}

// g[r][j][x][y] = sum_k cc[j,x,k] * dc[k,y]
__global__ __launch_bounds__(256) void k_g(const float* __restrict__ c1, const float* __restrict__ d1,
                                           const float* __restrict__ c2, const float* __restrict__ d2,
                                           float2* __restrict__ G) {
    int idx = blockIdx.x * 256 + threadIdx.x;      // < 262144
    int r = idx >> 17;
    int rem = idx & 131071;
    int j = rem >> 12;
    int xy = rem & 4095;
    int xm = xy >> 6, ym = xy & 63;
    const float* cp = r ? c2 : c1;
    const float* dp = r ? d2 : d1;
    float sr = 0.f, si = 0.f;
    for (int kk = 0; kk < 32; ++kk) {
        float cr = cp[((j * 64 + xm) * 32 + kk) * 2 + 0];
        float ci = cp[((j * 64 + xm) * 32 + kk) * 2 + 1];
        float dr = dp[(kk * 64 + ym) * 2 + 0];
        float di = dp[(kk * 64 + ym) * 2 + 1];
        sr = fmaf(cr, dr, fmaf(-ci, di, sr));
        si = fmaf(cr, di, fmaf( ci, dr, si));
    }
    G[(size_t)(r * 32 + j) * 4096 + xy] = make_float2(sr, si);
}

// bf16 fragment tables for the contraction.
__global__ __launch_bounds__(256) void k_prepBG(const float* __restrict__ b1, const float* __restrict__ b2,
                                                const float2* __restrict__ G,
                                                unsigned short* __restrict__ bA,
                                                unsigned short* __restrict__ gB) {
    size_t idx = (size_t)blockIdx.x * 256 + threadIdx.x;
    if (idx < 1048576) {
        int e     = idx & 7;
        int lane  = (idx >> 3) & 63;
        int c     = (idx >> 9) & 127;
        int itile = (idx >> 16) & 3;
        int reg   = (idx >> 18) & 1;
        int plane = (idx >> 19) & 1;
        int i = itile * 16 + (lane & 15);
        int j = 8 * (lane >> 4) + e;
        const float* bp = reg ? b2 : b1;
        float v = bp[((size_t)(i * 128 + c) * 32 + j) * 2 + plane];
        bA[idx] = f2bf(v);
    } else if (idx < 1048576 + 786432) {
        size_t i2 = idx - 1048576;
        int e     = i2 & 7;
        int lane  = (i2 >> 3) & 63;
        int ytile = (i2 >> 9) & 3;
        int x     = (i2 >> 11) & 63;
        int reg   = (i2 >> 17) & 1;
        int plane = (int)(i2 >> 18);           // 0,1,2
        int y = ytile * 16 + (lane & 15);
        int j = 8 * (lane >> 4) + e;
        float2 gv = G[(size_t)(reg * 32 + j) * 4096 + x * 64 + y];
        float v = (plane == 0) ? gv.x : ((plane == 1) ? gv.y : -gv.y);
        gB[i2] = f2bf(v);
    }
}

// Split-bf16 A-frag table for the a-epilogue GEMM (M=o=128, K=i=64).
// AFa[reg][pl(6: arh,arl,aih,ail,-aih,-ail)][kc(2)][rt(8)][lane][e]
__global__ __launch_bounds__(256) void k_prepA(const float* __restrict__ a1, const float* __restrict__ a2,
                                               unsigned short* __restrict__ AFa) {
    int idx = blockIdx.x * 256 + threadIdx.x;      // < 98304
    int e = idx & 7, lane = (idx >> 3) & 63;
    int rt = (idx >> 9) & 7, kc = (idx >> 12) & 1;
    int plreg = idx >> 13;                          // 0..11
    int reg = plreg / 6, pl = plreg % 6;
    int o = rt * 16 + (lane & 15);
    int i = kc * 32 + 8 * (lane >> 4) + e;
    const float* ap = reg ? a2 : a1;
    float ar = ap[(o * 64 + i) * 2 + 0];
    float ai = ap[(o * 64 + i) * 2 + 1];
    float base = (pl < 2) ? ar : ((pl < 4) ? ai : -ai);
    unsigned short hi = f2bf(base);
    unsigned short out = (pl & 1) ? f2bf(base - bf2f(hi)) : hi;
    AFa[idx] = out;
}

// MFMA W-DFT: block = 128 x-rows (4 waves x 2 mtiles) x 64 kw; K=256 (w), split-bf16.
__global__ __launch_bounds__(256) void k_stage1m(const float* __restrict__ x,
                                                 const unsigned short* __restrict__ BF,
                                                 unsigned short* __restrict__ Yt) {
    int t = threadIdx.x;
    int wave = t >> 6, lane = t & 63;
    size_t row0 = (size_t)blockIdx.x * 128 + (size_t)wave * 32;
    int colp = lane & 15, rowq = lane >> 4;
    const short8v* BFv = (const short8v*)BF;
    const size_t PLB = 8 * 4 * 64;

    float4v accR[2][4], accI[2][4];
#pragma unroll
    for (int rt = 0; rt < 2; ++rt)
#pragma unroll
        for (int nt = 0; nt < 4; ++nt) {
            accR[rt][nt] = (float4v){0.f, 0.f, 0.f, 0.f};
            accI[rt][nt] = (float4v){0.f, 0.f, 0.f, 0.f};
        }

    for (int kc = 0; kc < 8; ++kc) {
        short8v Bch[4], Bcl[4], Bsh[4], Bsl[4];
#pragma unroll
        for (int nt = 0; nt < 4; ++nt) {
            size_t bb = ((size_t)kc * 4 + nt) * 64 + lane;
            Bch[nt] = BFv[0 * PLB + bb];
            Bcl[nt] = BFv[1 * PLB + bb];
            Bsh[nt] = BFv[2 * PLB + bb];
            Bsl[nt] = BFv[3 * PLB + bb];
        }
#pragma unroll
        for (int rt = 0; rt < 2; ++rt) {
            const float* xp = x + (row0 + rt * 16 + colp) * 256 + kc * 32 + 8 * rowq;
            float4 v0 = *(const float4*)xp;
            float4 v1 = *(const float4*)(xp + 4);
            float vv[8] = {v0.x, v0.y, v0.z, v0.w, v1.x, v1.y, v1.z, v1.w};
            short8v xh, xl;
#pragma unroll
            for (int j = 0; j < 8; ++j) {
                unsigned short h = f2bf(vv[j]);
                xh[j] = (short)h;
                xl[j] = (short)f2bf(vv[j] - bf2f(h));
            }
#pragma unroll
            for (int nt = 0; nt < 4; ++nt) {
                float4v r_ = accR[rt][nt];
                r_ = __builtin_amdgcn_mfma_f32_16x16x32_bf16(xh, Bch[nt], r_, 0, 0, 0);
                r_ = __builtin_amdgcn_mfma_f32_16x16x32_bf16(xh, Bcl[nt], r_, 0, 0, 0);
                r_ = __builtin_amdgcn_mfma_f32_16x16x32_bf16(xl, Bch[nt], r_, 0, 0, 0);
                accR[rt][nt] = r_;
                float4v i_ = accI[rt][nt];
                i_ = __builtin_amdgcn_mfma_f32_16x16x32_bf16(xh, Bsh[nt], i_, 0, 0, 0);
                i_ = __builtin_amdgcn_mfma_f32_16x16x32_bf16(xh, Bsl[nt], i_, 0, 0, 0);
                i_ = __builtin_amdgcn_mfma_f32_16x16x32_bf16(xl, Bsh[nt], i_, 0, 0, 0);
                accI[rt][nt] = i_;
            }
        }
    }

    short* Yts = (short*)Yt;
    const size_t PLY = (size_t)32 * 32768 * 8;
#pragma unroll
    for (int rt = 0; rt < 2; ++rt) {
        size_t xrow = row0 + rt * 16 + rowq * 4;
        int h = (int)(xrow & 255), bc = (int)(xrow >> 8);
        size_t gbase = (size_t)(h >> 3) * 32768;
        int e0 = h & 7;
#pragma unroll
        for (int nt = 0; nt < 4; ++nt) {
            size_t p = (size_t)bc * 64 + nt * 16 + colp;
            size_t off = (gbase + p) * 8 + e0;
            float4v R = accR[rt][nt], I = accI[rt][nt];
            short rh[4], rl[4], ih[4], il[4];
#pragma unroll
            for (int q = 0; q < 4; ++q) {
                unsigned short h1 = f2bf(R[q]);
                rh[q] = (short)h1; rl[q] = (short)f2bf(R[q] - bf2f(h1));
                unsigned short h2 = f2bf(I[q]);
                ih[q] = (short)h2; il[q] = (short)f2bf(I[q] - bf2f(h2));
            }
            *(short4*)&Yts[0 * PLY + off] = make_short4(rh[0], rh[1], rh[2], rh[3]);
            *(short4*)&Yts[1 * PLY + off] = make_short4(rl[0], rl[1], rl[2], rl[3]);
            *(short4*)&Yts[2 * PLY + off] = make_short4(ih[0], ih[1], ih[2], ih[3]);
            *(short4*)&Yts[3 * PLY + off] = make_short4(il[0], il[1], il[2], il[3]);
        }
    }
}

// Split-bf16 complex MFMA GEMM: Out[r][p] = sum_s T[r][s] * D[s][p].
template<int S, int RT_W>
__global__ __launch_bounds__(256) void k_cmfma(const unsigned short* __restrict__ AF,
                                               const unsigned short* __restrict__ Bt,
                                               float2* __restrict__ Out) {
    constexpr int KC = S / 32;
    constexpr int SG = S / 8;
    constexpr int RTOT = RT_W * 4;
    __shared__ __align__(16) unsigned short bs[4 * SG * 16 * 8];
    int t = threadIdx.x;
    int wave = t >> 6, lane = t & 63;
    int rt0 = wave * RT_W;
    int colp = lane & 15, rowq = lane >> 4;
    const short8v* AFv = (const short8v*)AF;
    const short8v* bsv = (const short8v*)bs;
    const size_t PLA = (size_t)KC * RTOT * 64;

    for (int pt = 0; pt < 4; ++pt) {
        int p0 = blockIdx.x * 64 + pt * 16;
        __syncthreads();
        {
            const float4* src = (const float4*)Bt;
            float4* dst = (float4*)bs;
            for (int e = t; e < 4 * SG * 16; e += 256) {
                int pl = e / (SG * 16); int rem = e - pl * (SG * 16);
                int g = rem >> 4, li = rem & 15;
                dst[e] = src[((size_t)pl * SG + g) * 32768 + p0 + li];
            }
        }
        __syncthreads();
        float4v accR[RT_W], accI[RT_W];
#pragma unroll
        for (int rt = 0; rt < RT_W; ++rt) {
            accR[rt] = (float4v){0.f, 0.f, 0.f, 0.f};
            accI[rt] = (float4v){0.f, 0.f, 0.f, 0.f};
        }
#pragma unroll
        for (int kc = 0; kc < KC; ++kc) {
            int gi = kc * 4 + rowq;
            short8v Brh = bsv[((0 * SG + gi) << 4) + colp];
            short8v Brl = bsv[((1 * SG + gi) << 4) + colp];
            short8v Bih = bsv[((2 * SG + gi) << 4) + colp];
            short8v Bil = bsv[((3 * SG + gi) << 4) + colp];
#pragma unroll
            for (int rt = 0; rt < RT_W; ++rt) {
                size_t ab = ((size_t)kc * RTOT + rt0 + rt) * 64 + lane;
                short8v A0 = AFv[0 * PLA + ab];
                short8v A1 = AFv[1 * PLA + ab];
                short8v A2 = AFv[2 * PLA + ab];
                short8v A3 = AFv[3 * PLA + ab];
                short8v A4 = AFv[4 * PLA + ab];
                short8v A5 = AFv[5 * PLA + ab];
                float4v r_ = accR[rt];
                r_ = __builtin_amdgcn_mfma_f32_16x16x32_bf16(A0, Brh, r_, 0, 0, 0);
                r_ = __builtin_amdgcn_mfma_f32_16x16x32_bf16(A0, Brl, r_, 0, 0, 0);
                r_ = __builtin_amdgcn_mfma_f32_16x16x32_bf16(A1, Brh, r_, 0, 0, 0);
                r_ = __builtin_amdgcn_mfma_f32_16x16x32_bf16(A4, Bih, r_, 0, 0, 0);
                r_ = __builtin_amdgcn_mfma_f32_16x16x32_bf16(A4, Bil, r_, 0, 0, 0);
                r_ = __builtin_amdgcn_mfma_f32_16x16x32_bf16(A5, Bih, r_, 0, 0, 0);
                accR[rt] = r_;
                float4v i_ = accI[rt];
                i_ = __builtin_amdgcn_mfma_f32_16x16x32_bf16(A2, Brh, i_, 0, 0, 0);
                i_ = __builtin_amdgcn_mfma_f32_16x16x32_bf16(A2, Brl, i_, 0, 0, 0);
                i_ = __builtin_amdgcn_mfma_f32_16x16x32_bf16(A3, Brh, i_, 0, 0, 0);
                i_ = __builtin_amdgcn_mfma_f32_16x16x32_bf16(A0, Bih, i_, 0, 0, 0);
                i_ = __builtin_amdgcn_mfma_f32_16x16x32_bf16(A0, Bil, i_, 0, 0, 0);
                i_ = __builtin_amdgcn_mfma_f32_16x16x32_bf16(A1, Bih, i_, 0, 0, 0);
                accI[rt] = i_;
            }
        }
#pragma unroll
        for (int rt = 0; rt < RT_W; ++rt) {
            int rbase = (rt0 + rt) * 16 + rowq * 4;
#pragma unroll
            for (int q = 0; q < 4; ++q)
                Out[(size_t)(rbase + q) * P_ + p0 + colp] = make_float2(accR[rt][q], accI[rt][q]);
        }
    }
}

// MFMA contract, phase A: per (k, ytile), no LDS, no barriers.
//   per c: w = b*g via 4 MFMAs; t[i,b,m] += w * xf[b,c,m] (fp32 VALU)
// t written as split-bf16 B-frag planes tA[pl][i>>3][(k,b,m)][i&7].
__global__ __launch_bounds__(256) void k_contractA(const float2* __restrict__ XF,
                                                   const unsigned short* __restrict__ bA,
                                                   const unsigned short* __restrict__ gB,
                                                   unsigned short* __restrict__ tA) {
    int t = threadIdx.x;
    int k = blockIdx.x >> 2;
    int ytile = blockIdx.x & 3;
    int y0 = ytile << 4;
    int reg = (k >= 64) ? 1 : 0;
    int x = k & 63;
    int itile = t >> 6, lane = t & 63;
    int ylane = lane & 15, qg = lane >> 4;

    const short8v* gBv = (const short8v*)gB;
    short8v g_r  = gBv[(((size_t)(0 * 2 + reg) * 64 + x) * 4 + ytile) * 64 + lane];
    short8v g_i  = gBv[(((size_t)(1 * 2 + reg) * 64 + x) * 4 + ytile) * 64 + lane];
    short8v g_ni = gBv[(((size_t)(2 * 2 + reg) * 64 + x) * 4 + ytile) * 64 + lane];

    const short8v* bAv = (const short8v*)bA;
    size_t aR = (((size_t)(0 * 2 + reg) * 4 + itile) * 128) * 64 + lane;
    size_t aI = (((size_t)(1 * 2 + reg) * 4 + itile) * 128) * 64 + lane;

    const float2* xfp = XF + (size_t)k * 32768 + y0 + ylane;

    float tr[4][4], ti[4][4];
#pragma unroll
    for (int q = 0; q < 4; ++q)
#pragma unroll
        for (int b = 0; b < 4; ++b) { tr[q][b] = 0.f; ti[q][b] = 0.f; }

#pragma unroll 2
    for (int c = 0; c < 128; ++c) {
        short8v av = bAv[aR + (size_t)c * 64];
        short8v aw = bAv[aI + (size_t)c * 64];
        float4v z4 = {0.f, 0.f, 0.f, 0.f};
        float4v wr = __builtin_amdgcn_mfma_f32_16x16x32_bf16(av, g_r, z4, 0, 0, 0);
        wr = __builtin_amdgcn_mfma_f32_16x16x32_bf16(aw, g_ni, wr, 0, 0, 0);
        float4v wi = __builtin_amdgcn_mfma_f32_16x16x32_bf16(av, g_i, z4, 0, 0, 0);
        wi = __builtin_amdgcn_mfma_f32_16x16x32_bf16(aw, g_r, wi, 0, 0, 0);
#pragma unroll
        for (int b = 0; b < 4; ++b) {
            float2 xv = xfp[(size_t)b * 8192 + (size_t)c * 64];
#pragma unroll
            for (int q = 0; q < 4; ++q) {
                tr[q][b] = fmaf(wr[q], xv.x, fmaf(-wi[q], xv.y, tr[q][b]));
                ti[q][b] = fmaf(wr[q], xv.y, fmaf( wi[q], xv.x, ti[q][b]));
            }
        }
    }

    // write t as split-bf16 frag planes: i = itile*16 + qg*4 + q -> group g, elem e
    short* tAs = (short*)tA;
    const size_t PLT = (size_t)8 * 32768 * 8;     // plane stride in shorts
    int gidx = itile * 2 + (qg >> 1);
    int e0 = (qg & 1) * 4;
#pragma unroll
    for (int b = 0; b < 4; ++b) {
        size_t col = (size_t)k * 256 + (size_t)b * 64 + y0 + ylane;
        size_t off = ((size_t)gidx * 32768 + col) * 8 + e0;
        short rh[4], rl[4], ih[4], il[4];
#pragma unroll
        for (int q = 0; q < 4; ++q) {
            unsigned short h1 = f2bf(tr[q][b]);
            rh[q] = (short)h1; rl[q] = (short)f2bf(tr[q][b] - bf2f(h1));
            unsigned short h2 = f2bf(ti[q][b]);
            ih[q] = (short)h2; il[q] = (short)f2bf(ti[q][b] - bf2f(h2));
        }
        *(short4*)&tAs[0 * PLT + off] = make_short4(rh[0], rh[1], rh[2], rh[3]);
        *(short4*)&tAs[1 * PLT + off] = make_short4(rl[0], rl[1], rl[2], rl[3]);
        *(short4*)&tAs[2 * PLT + off] = make_short4(ih[0], ih[1], ih[2], ih[3]);
        *(short4*)&tAs[3 * PLT + off] = make_short4(il[0], il[1], il[2], il[3]);
    }
}

// MFMA contract, phase B: OF[o, (k,b,m)] = sum_i a[o,i] * t[i, (k,b,m)].
// Block = (k,b) (grid 512); 4 waves x 2 rtiles = 128 o rows; cols = m (4 pt x 16).
__global__ __launch_bounds__(256) void k_amfma(const unsigned short* __restrict__ AFa,
                                               const unsigned short* __restrict__ tA,
                                               float2* __restrict__ OF) {
    constexpr int SG = 8;                          // 64 i-rows / 8
    __shared__ __align__(16) unsigned short bs[4 * SG * 16 * 8];   // 8KB
    int t = threadIdx.x;
    int wave = t >> 6, lane = t & 63;
    int rt0 = wave * 2;
    int colp = lane & 15, rowq = lane >> 4;
    int k = blockIdx.x >> 2, b = blockIdx.x & 3;
    int reg = (k >= 64) ? 1 : 0;
    const short8v* AFv = (const short8v*)(AFa + (size_t)reg * 6 * 2 * 8 * 512);
    const size_t PLA = 2 * 8 * 64;                 // per-plane stride (short8 units)
    const short8v* bsv = (const short8v*)bs;
    size_t p0 = (size_t)blockIdx.x * 64;

    for (int pt = 0; pt < 4; ++pt) {
        __syncthreads();
        {   // stage 4 planes x 8 groups x 16 cols
            const float4* src = (const float4*)tA;
            float4* dst = (float4*)bs;
            for (int e = t; e < 4 * SG * 16; e += 256) {
                int pl = e >> 7; int rem = e & 127;
                int g = rem >> 4, li = rem & 15;
                dst[e] = src[((size_t)pl * SG + g) * 32768 + p0 + pt * 16 + li];
            }
        }
        __syncthreads();
        float4v accR[2], accI[2];
#pragma unroll
        for (int rt = 0; rt < 2; ++rt) {
            accR[rt] = (float4v){0.f, 0.f, 0.f, 0.f};
            accI[rt] = (float4v){0.f, 0.f, 0.f, 0.f};
        }
#pragma unroll
        for (int kc = 0; kc < 2; ++kc) {
            int gi = kc * 4 + rowq;
            short8v Brh = bsv[((0 * SG + gi) << 4) + colp];
            short8v Brl = bsv[((1 * SG + gi) << 4) + colp];
            short8v Bih = bsv[((2 * SG + gi) << 4) + colp];
            short8v Bil = bsv[((3 * SG + gi) << 4) + colp];
#pragma unroll
            for (int rt = 0; rt < 2; ++rt) {
                size_t ab = ((size_t)kc * 8 + rt0 + rt) * 64 + lane;
                short8v A0 = AFv[0 * PLA + ab];
                short8v A1 = AFv[1 * PLA + ab];
                short8v A2 = AFv[2 * PLA + ab];
                short8v A3 = AFv[3 * PLA + ab];
                short8v A4 = AFv[4 * PLA + ab];
                short8v A5 = AFv[5 * PLA + ab];
                float4v r_ = accR[rt];
                r_ = __builtin_amdgcn_mfma_f32_16x16x32_bf16(A0, Brh, r_, 0, 0, 0);
                r_ = __builtin_amdgcn_mfma_f32_16x16x32_bf16(A0, Brl, r_, 0, 0, 0);
                r_ = __builtin_amdgcn_mfma_f32_16x16x32_bf16(A1, Brh, r_, 0, 0, 0);
                r_ = __builtin_amdgcn_mfma_f32_16x16x32_bf16(A4, Bih, r_, 0, 0, 0);
                r_ = __builtin_amdgcn_mfma_f32_16x16x32_bf16(A4, Bil, r_, 0, 0, 0);
                r_ = __builtin_amdgcn_mfma_f32_16x16x32_bf16(A5, Bih, r_, 0, 0, 0);
                accR[rt] = r_;
                float4v i_ = accI[rt];
                i_ = __builtin_amdgcn_mfma_f32_16x16x32_bf16(A2, Brh, i_, 0, 0, 0);
                i_ = __builtin_amdgcn_mfma_f32_16x16x32_bf16(A2, Brl, i_, 0, 0, 0);
                i_ = __builtin_amdgcn_mfma_f32_16x16x32_bf16(A3, Brh, i_, 0, 0, 0);
                i_ = __builtin_amdgcn_mfma_f32_16x16x32_bf16(A0, Bih, i_, 0, 0, 0);
                i_ = __builtin_amdgcn_mfma_f32_16x16x32_bf16(A0, Bil, i_, 0, 0, 0);
                i_ = __builtin_amdgcn_mfma_f32_16x16x32_bf16(A1, Bih, i_, 0, 0, 0);
                accI[rt] = i_;
            }
        }
        int m = pt * 16 + colp;
#pragma unroll
        for (int rt = 0; rt < 2; ++rt) {
            int o0 = (rt0 + rt) * 16 + rowq * 4;
#pragma unroll
            for (int q = 0; q < 4; ++q)
                OF[(size_t)k * 32768 + (size_t)b * 8192 + (size_t)(o0 + q) * 64 + m] =
                    make_float2(accR[rt][q], accI[rt][q]);
        }
    }
}

// OF fp32 [k][p] -> OFt 4 bf16 planes [k>>3][p][k&7]
__global__ __launch_bounds__(256) void k_repack(const float2* __restrict__ OF,
                                                unsigned short* __restrict__ OFt) {
    int t = threadIdx.x;
    size_t p = (size_t)blockIdx.x * 256 + t;
    int kg = blockIdx.y;
    short8v vrh, vrl, vih, vil;
#pragma unroll
    for (int j = 0; j < 8; ++j) {
        float2 v = OF[(size_t)(kg * 8 + j) * P_ + p];
        unsigned short h1 = f2bf(v.x);
        vrh[j] = (short)h1; vrl[j] = (short)f2bf(v.x - bf2f(h1));
        unsigned short h2 = f2bf(v.y);
        vih[j] = (short)h2; vil[j] = (short)f2bf(v.y - bf2f(h2));
    }
    short8v* dst = (short8v*)OFt;
    const size_t PL8 = (size_t)16 * 32768;
    size_t gi = (size_t)kg * 32768 + p;
    dst[0 * PL8 + gi] = vrh;
    dst[1 * PL8 + gi] = vrl;
    dst[2 * PL8 + gi] = vih;
    dst[3 * PL8 + gi] = vil;
}

// out[b,o,h,w'] from Z[h][b][o][kw] using radix-4 symmetry over w.
__global__ __launch_bounds__(256) void k_invW(const float2* __restrict__ Z,
                                              const float2* __restrict__ IW,
                                              float* __restrict__ out) {
    __shared__ __align__(16) float2 zs[16][64];
    int t = threadIdx.x;
    int w = t & 63, rs = t >> 6;
    size_t row0 = (size_t)blockIdx.x * 16;
    {
        const float4* src = (const float4*)(Z + row0 * 64);
        float4* dst = (float4*)zs;
        dst[t] = src[t];
        dst[t + 256] = src[t + 256];
    }
    __syncthreads();

    float sr[4][4], si[4][4];
#pragma unroll
    for (int pp = 0; pp < 4; ++pp)
#pragma unroll
        for (int m = 0; m < 4; ++m) { sr[pp][m] = 0.f; si[pp][m] = 0.f; }

#pragma unroll
    for (int kwh = 0; kwh < 2; ++kwh) {
        float2 IWr[32];
#pragma unroll
        for (int q = 0; q < 32; ++q) IWr[q] = IW[(kwh * 32 + q) * 64 + w];
#pragma unroll
        for (int pass = 0; pass < 4; ++pass) {
            int r = rs * 4 + pass;
            const float4* zrow = (const float4*)&zs[r][kwh * 32];
#pragma unroll
            for (int q = 0; q < 16; ++q) {
                float4 zq = zrow[q];
                float2 f0 = IWr[2 * q], f1 = IWr[2 * q + 1];
                if ((q & 1) == 0) {
                    sr[pass][0] = fmaf(zq.x, f0.x, fmaf(-zq.y, f0.y, sr[pass][0]));
                    si[pass][0] = fmaf(zq.x, f0.y, fmaf( zq.y, f0.x, si[pass][0]));
                    sr[pass][1] = fmaf(zq.z, f1.x, fmaf(-zq.w, f1.y, sr[pass][1]));
                    si[pass][1] = fmaf(zq.z, f1.y, fmaf( zq.w, f1.x, si[pass][1]));
                } else {
                    sr[pass][2] = fmaf(zq.x, f0.x, fmaf(-zq.y, f0.y, sr[pass][2]));
                    si[pass][2] = fmaf(zq.x, f0.y, fmaf( zq.y, f0.x, si[pass][2]));
                    sr[pass][3] = fmaf(zq.z, f1.x, fmaf(-zq.w, f1.y, sr[pass][3]));
                    si[pass][3] = fmaf(zq.z, f1.y, fmaf( zq.w, f1.x, si[pass][3]));
                }
            }
        }
    }

#pragma unroll
    for (int pass = 0; pass < 4; ++pass) {
        int r = rs * 4 + pass;
        size_t row = row0 + r;
        int h = (int)(row >> 9);
        int rem = (int)(row & 511);
        int b = rem >> 7, o = rem & 127;
        float s0r = sr[pass][0], s1r = sr[pass][1], s2r = sr[pass][2], s3r = sr[pass][3];
        float s1i = si[pass][1], s3i = si[pass][3];
        float o0 = s0r + s1r + s2r + s3r;
        float o1 = s0r - s1i - s2r + s3i;
        float o2 = s0r - s1r + s2r - s3r;
        float o3 = s0r + s1i - s2r - s3i;
        size_t base = (((size_t)(b * 128 + o)) * 256 + h) * 256 + w;
        out[base + 0]   = o0;
        out[base + 64]  = o1;
        out[base + 128] = o2;
        out[base + 192] = o3;
    }
}

extern "C" void kernel_launch(void* const* d_in, const int* in_sizes, int n_in,
                              void* d_out, int out_size, void* d_ws, size_t ws_size,
                              hipStream_t stream) {
    const float* x  = (const float*)d_in[0];
    const float* a1 = (const float*)d_in[1];
    const float* b1 = (const float*)d_in[2];
    const float* c1 = (const float*)d_in[3];
    const float* d1 = (const float*)d_in[4];
    const float* a2 = (const float*)d_in[5];
    const float* b2 = (const float*)d_in[6];
    const float* c2 = (const float*)d_in[7];
    const float* d2 = (const float*)d_in[8];
    float* out = (float*)d_out;
    float* wsf = (float*)d_ws;

    if (ws_size < WS_FLOATS * sizeof(float)) return;

    unsigned short* Yt  = (unsigned short*)(wsf + oYT);
    float2*         Zb  = (float2*)(wsf + oYT);          // Z aliases Yt region (after amfma)
    float2*         XF  = (float2*)(wsf + oXF);
    unsigned short* OFt = (unsigned short*)(wsf + oXF);  // OFt aliases XF (after contractA)
    float2*         OF  = (float2*)(wsf + oOF);
    float2*         IW  = (float2*)(wsf + oIW);
    float2*         G   = (float2*)(wsf + oG);
    unsigned short* BF  = (unsigned short*)(wsf + oBF);
    unsigned short* AF1 = (unsigned short*)(wsf + oAF1);
    unsigned short* AF2 = (unsigned short*)(wsf + oAF2);
    unsigned short* bA  = (unsigned short*)(wsf + oYT);  // after cmfma1, Yt region is dead
    unsigned short* gB  = bA + 1048576;
    unsigned short* tA  = (unsigned short*)(wsf + oTA);  // after bA/gB, inside dead Yt region
    unsigned short* AFa = (unsigned short*)(wsf + oG);   // overwrites G after prepBG

    k_twiddle<<<16, 256, 0, stream>>>(wsf);
    k_prepT<<<1792, 256, 0, stream>>>(AF1, AF2, BF);
    k_g<<<1024, 256, 0, stream>>>(c1, d1, c2, d2, G);
    k_stage1m<<<1024, 256, 0, stream>>>(x, BF, Yt);
    k_cmfma<256, 2><<<512, 256, 0, stream>>>(AF1, Yt, XF);
    k_prepBG<<<7168, 256, 0, stream>>>(b1, b2, G, bA, gB);
    k_prepA<<<384, 256, 0, stream>>>(a1, a2, AFa);       // G dead after prepBG
    k_contractA<<<512, 256, 0, stream>>>(XF, bA, gB, tA);
    k_amfma<<<512, 256, 0, stream>>>(AFa, tA, OF);
    k_repack<<<dim3(128, 16), 256, 0, stream>>>(OF, OFt);
    k_cmfma<128, 4><<<512, 256, 0, stream>>>(AF2, OFt, Zb);
    k_invW<<<8192, 256, 0, stream>>>(Zb, IW, out);

    (void)in_sizes; (void)n_in; (void)out_size;
}

// Round 9
// 297.034 us; speedup vs baseline: 5.9592x; 1.1161x over previous
//
#include <hip/hip_runtime.h>
#include <math.h>

// FactorizedSpectralConv2d: pruned-DFT + TT contraction, MFMA everywhere matmul-shaped.
//
//   k_prepT    : split-bf16 MFMA A-frag tables for FH / IH DFT matrices + B-frag table for FW
//   k_g        : g[r][j][x][y] = sum_k cc[j,x,k]*dc[k,y]
//   k_stage1m  : W-DFT of x via split-bf16 MFMA -> Yt 4 bf16 planes [h/8][p][8]
//   k_cmfma    : XF[k][p] = sum_h FH[k][h] Yt[h][p]    (split-bf16 complex MFMA)
//   k_prepBG   : bf16 frag tables for b (A) and g (B) of the TT contraction
//   k_prepA    : split-bf16 A-frag table for the a (Cout x r1) epilogue GEMM (over dead G)
//   k_contractA: MFMA w-GEMM + fp32 t-update; t written as split-bf16 frag planes tA
//   k_amfma    : OF[o,(k,b,m)] = sum_i a[o,i] tA[i,(k,b,m)]   (split-bf16 MFMA)
//   k_repack   : OF fp32 -> OFt 4 bf16 planes [k/8][p][8]
//   k_prepE    : bf16 B-frag table for the inverse-W twiddle (into dead OF region)
//   k_cmfma    : Z[h][q] = sum_k IH[h][k] OFt[k][q]
//   k_invWm    : out[(b,o,h)][w] = Re(Z . E) via MFMA (Z split hi/lo on the fly)

#define TWO_PI 6.28318530717958647692f

typedef __attribute__((ext_vector_type(8))) short short8v;   // 8 bf16 (4 VGPRs)
typedef __attribute__((ext_vector_type(4))) float float4v;   // MFMA C/D

namespace {
constexpr size_t P_ = 32768;            // B*C*KW pixel batch width

// workspace float offsets
constexpr size_t oYT = 0;                     // Yt: 4 planes [32][32768][8] bf16 = 16.77M floats
                                              //   then bA/gB + tA (contract), then Z f2
constexpr size_t oTA = 1048576;               // tA: 4 planes [8][32768][8] bf16
constexpr size_t oXF = 16777216;              // XF f2 33.5MB; later OFt 4 planes [16][32768][8]
constexpr size_t oOF = 25165824;              // OF f2 33.5MB; later EF (invW twiddle frags)
constexpr size_t oBF = 33554432;              // FW B-frag table: 65536 shorts
constexpr size_t oAF1 = 33587200;             // FH frags: 196608 shorts
constexpr size_t oAF2 = 33685504;             // IH frags
constexpr size_t oG  = 33792000;              // [2][32][64][64] f2 ; AFa overwrites after prepBG
constexpr size_t WS_FLOATS = oG + 524288;     // ~137.3 MB
}

__device__ __forceinline__ unsigned short f2bf(float f) {   // RNE float->bf16 bits
    unsigned int u = __float_as_uint(f);
    unsigned int r = (u + 0x7FFFu + ((u >> 16) & 1u)) >> 16;
    return (unsigned short)r;
}
__device__ __forceinline__ float bf2f(unsigned short b) {
    return __uint_as_float(((unsigned int)b) << 16);
}

// Split-bf16 fragment tables for the DFT matrices (AF1 FH, AF2 IH, BF FW).
__global__ __launch_bounds__(256) void k_prepT(unsigned short* __restrict__ AF1,
                                               unsigned short* __restrict__ AF2,
                                               unsigned short* __restrict__ BF) {
    int idx = blockIdx.x * 256 + threadIdx.x;      // < 458752
    if (idx < 393216) {
        int tbl = (idx >= 196608);
        int id = tbl ? (idx - 196608) : idx;
        int e = id & 7, lane = (id >> 3) & 63;
        int pl = id >> 15;
        float ang;
        if (!tbl) {
            int rt = (id >> 9) & 7, kc = (id >> 12) & 7;
            int r = rt * 16 + (lane & 15);             // k-row (128)
            int s = kc * 32 + 8 * (lane >> 4) + e;     // h (256)
            int kh = r + ((r >= 64) ? 128 : 0);
            int ph = (kh * s) & 255;
            ang = -TWO_PI * (float)ph / 256.0f;
        } else {
            int rt = (id >> 9) & 15, kc = (id >> 13) & 3;
            int r = rt * 16 + (lane & 15);             // h (256)
            int s = kc * 32 + 8 * (lane >> 4) + e;     // k (128)
            int kh = s + ((s >= 64) ? 128 : 0);
            int ph = (kh * r) & 255;
            ang = TWO_PI * (float)ph / 256.0f;
        }
        float sn, cs; sincosf(ang, &sn, &cs);
        float base = (pl < 2) ? cs : ((pl < 4) ? sn : -sn);
        unsigned short hi = f2bf(base);
        unsigned short out = (pl & 1) ? f2bf(base - bf2f(hi)) : hi;
        (tbl ? AF2 : AF1)[id] = out;
    } else {
        int id = idx - 393216;                          // < 65536
        int e = id & 7, lane = (id >> 3) & 63;
        int nt = (id >> 9) & 3, kc = (id >> 11) & 7;
        int pl = id >> 14;                              // 0..3
        int kw = nt * 16 + (lane & 15);
        int w = kc * 32 + 8 * (lane >> 4) + e;
        int ph = (w * kw) & 255;
        float ang = -TWO_PI * (float)ph / 256.0f;
        float sn, cs; sincosf(ang, &sn, &cs);
        float base = (pl < 2) ? cs : sn;
        unsigned short hi = f2bf(base);
        unsigned short out = (pl & 1) ? f2bf(base - bf2f(hi)) : hi;
        BF[id] = out;
    }
}

// bf16-hi B-frag table for the inverse-W twiddle:
// EF[pl(2: Er, -Ei)][kc(2)][nt(16)][lane][e], E[kw][w] = s_kw/65536 * e^{+2pi i kw w/256}
__global__ __launch_bounds__(256) void k_prepE(unsigned short* __restrict__ EF) {
    int idx = blockIdx.x * 256 + threadIdx.x;      // < 32768
    int e = idx & 7, lane = (idx >> 3) & 63;
    int nt = (idx >> 9) & 15, kc = (idx >> 13) & 1, pl = idx >> 14;
    int w = nt * 16 + (lane & 15);
    int kw = kc * 32 + 8 * (lane >> 4) + e;
    int ph = (kw * w) & 255;
    float ang = TWO_PI * (float)ph / 256.0f;
    float sn, cs; sincosf(ang, &sn, &cs);
    float sc = ((kw == 0) ? 1.0f : 2.0f) / 65536.0f;
    float v = (pl == 0) ? (sc * cs) : (-sc * sn);
    EF[idx] = f2bf(v);
}

// g[r][j][x][y] = sum_k cc[j,x,k] * dc[k,y]
__global__ __launch_bounds__(256) void k_g(const float* __restrict__ c1, const float* __restrict__ d1,
                                           const float* __restrict__ c2, const float* __restrict__ d2,
                                           float2* __restrict__ G) {
    int idx = blockIdx.x * 256 + threadIdx.x;      // < 262144
    int r = idx >> 17;
    int rem = idx & 131071;
    int j = rem >> 12;
    int xy = rem & 4095;
    int xm = xy >> 6, ym = xy & 63;
    const float* cp = r ? c2 : c1;
    const float* dp = r ? d2 : d1;
    float sr = 0.f, si = 0.f;
    for (int kk = 0; kk < 32; ++kk) {
        float cr = cp[((j * 64 + xm) * 32 + kk) * 2 + 0];
        float ci = cp[((j * 64 + xm) * 32 + kk) * 2 + 1];
        float dr = dp[(kk * 64 + ym) * 2 + 0];
        float di = dp[(kk * 64 + ym) * 2 + 1];
        sr = fmaf(cr, dr, fmaf(-ci, di, sr));
        si = fmaf(cr, di, fmaf( ci, dr, si));
    }
    G[(size_t)(r * 32 + j) * 4096 + xy] = make_float2(sr, si);
}

// bf16 fragment tables for the contraction.
__global__ __launch_bounds__(256) void k_prepBG(const float* __restrict__ b1, const float* __restrict__ b2,
                                                const float2* __restrict__ G,
                                                unsigned short* __restrict__ bA,
                                                unsigned short* __restrict__ gB) {
    size_t idx = (size_t)blockIdx.x * 256 + threadIdx.x;
    if (idx < 1048576) {
        int e     = idx & 7;
        int lane  = (idx >> 3) & 63;
        int c     = (idx >> 9) & 127;
        int itile = (idx >> 16) & 3;
        int reg   = (idx >> 18) & 1;
        int plane = (idx >> 19) & 1;
        int i = itile * 16 + (lane & 15);
        int j = 8 * (lane >> 4) + e;
        const float* bp = reg ? b2 : b1;
        float v = bp[((size_t)(i * 128 + c) * 32 + j) * 2 + plane];
        bA[idx] = f2bf(v);
    } else if (idx < 1048576 + 786432) {
        size_t i2 = idx - 1048576;
        int e     = i2 & 7;
        int lane  = (i2 >> 3) & 63;
        int ytile = (i2 >> 9) & 3;
        int x     = (i2 >> 11) & 63;
        int reg   = (i2 >> 17) & 1;
        int plane = (int)(i2 >> 18);           // 0,1,2
        int y = ytile * 16 + (lane & 15);
        int j = 8 * (lane >> 4) + e;
        float2 gv = G[(size_t)(reg * 32 + j) * 4096 + x * 64 + y];
        float v = (plane == 0) ? gv.x : ((plane == 1) ? gv.y : -gv.y);
        gB[i2] = f2bf(v);
    }
}

// Split-bf16 A-frag table for the a-epilogue GEMM (M=o=128, K=i=64).
__global__ __launch_bounds__(256) void k_prepA(const float* __restrict__ a1, const float* __restrict__ a2,
                                               unsigned short* __restrict__ AFa) {
    int idx = blockIdx.x * 256 + threadIdx.x;      // < 98304
    int e = idx & 7, lane = (idx >> 3) & 63;
    int rt = (idx >> 9) & 7, kc = (idx >> 12) & 1;
    int plreg = idx >> 13;                          // 0..11
    int reg = plreg / 6, pl = plreg % 6;
    int o = rt * 16 + (lane & 15);
    int i = kc * 32 + 8 * (lane >> 4) + e;
    const float* ap = reg ? a2 : a1;
    float ar = ap[(o * 64 + i) * 2 + 0];
    float ai = ap[(o * 64 + i) * 2 + 1];
    float base = (pl < 2) ? ar : ((pl < 4) ? ai : -ai);
    unsigned short hi = f2bf(base);
    unsigned short out = (pl & 1) ? f2bf(base - bf2f(hi)) : hi;
    AFa[idx] = out;
}

// MFMA W-DFT: block = 128 x-rows (4 waves x 2 mtiles) x 64 kw; K=256 (w), split-bf16.
__global__ __launch_bounds__(256) void k_stage1m(const float* __restrict__ x,
                                                 const unsigned short* __restrict__ BF,
                                                 unsigned short* __restrict__ Yt) {
    int t = threadIdx.x;
    int wave = t >> 6, lane = t & 63;
    size_t row0 = (size_t)blockIdx.x * 128 + (size_t)wave * 32;
    int colp = lane & 15, rowq = lane >> 4;
    const short8v* BFv = (const short8v*)BF;
    const size_t PLB = 8 * 4 * 64;

    float4v accR[2][4], accI[2][4];
#pragma unroll
    for (int rt = 0; rt < 2; ++rt)
#pragma unroll
        for (int nt = 0; nt < 4; ++nt) {
            accR[rt][nt] = (float4v){0.f, 0.f, 0.f, 0.f};
            accI[rt][nt] = (float4v){0.f, 0.f, 0.f, 0.f};
        }

    for (int kc = 0; kc < 8; ++kc) {
        short8v Bch[4], Bcl[4], Bsh[4], Bsl[4];
#pragma unroll
        for (int nt = 0; nt < 4; ++nt) {
            size_t bb = ((size_t)kc * 4 + nt) * 64 + lane;
            Bch[nt] = BFv[0 * PLB + bb];
            Bcl[nt] = BFv[1 * PLB + bb];
            Bsh[nt] = BFv[2 * PLB + bb];
            Bsl[nt] = BFv[3 * PLB + bb];
        }
#pragma unroll
        for (int rt = 0; rt < 2; ++rt) {
            const float* xp = x + (row0 + rt * 16 + colp) * 256 + kc * 32 + 8 * rowq;
            float4 v0 = *(const float4*)xp;
            float4 v1 = *(const float4*)(xp + 4);
            float vv[8] = {v0.x, v0.y, v0.z, v0.w, v1.x, v1.y, v1.z, v1.w};
            short8v xh, xl;
#pragma unroll
            for (int j = 0; j < 8; ++j) {
                unsigned short h = f2bf(vv[j]);
                xh[j] = (short)h;
                xl[j] = (short)f2bf(vv[j] - bf2f(h));
            }
#pragma unroll
            for (int nt = 0; nt < 4; ++nt) {
                float4v r_ = accR[rt][nt];
                r_ = __builtin_amdgcn_mfma_f32_16x16x32_bf16(xh, Bch[nt], r_, 0, 0, 0);
                r_ = __builtin_amdgcn_mfma_f32_16x16x32_bf16(xh, Bcl[nt], r_, 0, 0, 0);
                r_ = __builtin_amdgcn_mfma_f32_16x16x32_bf16(xl, Bch[nt], r_, 0, 0, 0);
                accR[rt][nt] = r_;
                float4v i_ = accI[rt][nt];
                i_ = __builtin_amdgcn_mfma_f32_16x16x32_bf16(xh, Bsh[nt], i_, 0, 0, 0);
                i_ = __builtin_amdgcn_mfma_f32_16x16x32_bf16(xh, Bsl[nt], i_, 0, 0, 0);
                i_ = __builtin_amdgcn_mfma_f32_16x16x32_bf16(xl, Bsh[nt], i_, 0, 0, 0);
                accI[rt][nt] = i_;
            }
        }
    }

    short* Yts = (short*)Yt;
    const size_t PLY = (size_t)32 * 32768 * 8;
#pragma unroll
    for (int rt = 0; rt < 2; ++rt) {
        size_t xrow = row0 + rt * 16 + rowq * 4;
        int h = (int)(xrow & 255), bc = (int)(xrow >> 8);
        size_t gbase = (size_t)(h >> 3) * 32768;
        int e0 = h & 7;
#pragma unroll
        for (int nt = 0; nt < 4; ++nt) {
            size_t p = (size_t)bc * 64 + nt * 16 + colp;
            size_t off = (gbase + p) * 8 + e0;
            float4v R = accR[rt][nt], I = accI[rt][nt];
            short rh[4], rl[4], ih[4], il[4];
#pragma unroll
            for (int q = 0; q < 4; ++q) {
                unsigned short h1 = f2bf(R[q]);
                rh[q] = (short)h1; rl[q] = (short)f2bf(R[q] - bf2f(h1));
                unsigned short h2 = f2bf(I[q]);
                ih[q] = (short)h2; il[q] = (short)f2bf(I[q] - bf2f(h2));
            }
            *(short4*)&Yts[0 * PLY + off] = make_short4(rh[0], rh[1], rh[2], rh[3]);
            *(short4*)&Yts[1 * PLY + off] = make_short4(rl[0], rl[1], rl[2], rl[3]);
            *(short4*)&Yts[2 * PLY + off] = make_short4(ih[0], ih[1], ih[2], ih[3]);
            *(short4*)&Yts[3 * PLY + off] = make_short4(il[0], il[1], il[2], il[3]);
        }
    }
}

// Split-bf16 complex MFMA GEMM: Out[r][p] = sum_s T[r][s] * D[s][p].
template<int S, int RT_W>
__global__ __launch_bounds__(256) void k_cmfma(const unsigned short* __restrict__ AF,
                                               const unsigned short* __restrict__ Bt,
                                               float2* __restrict__ Out) {
    constexpr int KC = S / 32;
    constexpr int SG = S / 8;
    constexpr int RTOT = RT_W * 4;
    __shared__ __align__(16) unsigned short bs[4 * SG * 16 * 8];
    int t = threadIdx.x;
    int wave = t >> 6, lane = t & 63;
    int rt0 = wave * RT_W;
    int colp = lane & 15, rowq = lane >> 4;
    const short8v* AFv = (const short8v*)AF;
    const short8v* bsv = (const short8v*)bs;
    const size_t PLA = (size_t)KC * RTOT * 64;

    for (int pt = 0; pt < 4; ++pt) {
        int p0 = blockIdx.x * 64 + pt * 16;
        __syncthreads();
        {
            const float4* src = (const float4*)Bt;
            float4* dst = (float4*)bs;
            for (int e = t; e < 4 * SG * 16; e += 256) {
                int pl = e / (SG * 16); int rem = e - pl * (SG * 16);
                int g = rem >> 4, li = rem & 15;
                dst[e] = src[((size_t)pl * SG + g) * 32768 + p0 + li];
            }
        }
        __syncthreads();
        float4v accR[RT_W], accI[RT_W];
#pragma unroll
        for (int rt = 0; rt < RT_W; ++rt) {
            accR[rt] = (float4v){0.f, 0.f, 0.f, 0.f};
            accI[rt] = (float4v){0.f, 0.f, 0.f, 0.f};
        }
#pragma unroll
        for (int kc = 0; kc < KC; ++kc) {
            int gi = kc * 4 + rowq;
            short8v Brh = bsv[((0 * SG + gi) << 4) + colp];
            short8v Brl = bsv[((1 * SG + gi) << 4) + colp];
            short8v Bih = bsv[((2 * SG + gi) << 4) + colp];
            short8v Bil = bsv[((3 * SG + gi) << 4) + colp];
#pragma unroll
            for (int rt = 0; rt < RT_W; ++rt) {
                size_t ab = ((size_t)kc * RTOT + rt0 + rt) * 64 + lane;
                short8v A0 = AFv[0 * PLA + ab];
                short8v A1 = AFv[1 * PLA + ab];
                short8v A2 = AFv[2 * PLA + ab];
                short8v A3 = AFv[3 * PLA + ab];
                short8v A4 = AFv[4 * PLA + ab];
                short8v A5 = AFv[5 * PLA + ab];
                float4v r_ = accR[rt];
                r_ = __builtin_amdgcn_mfma_f32_16x16x32_bf16(A0, Brh, r_, 0, 0, 0);
                r_ = __builtin_amdgcn_mfma_f32_16x16x32_bf16(A0, Brl, r_, 0, 0, 0);
                r_ = __builtin_amdgcn_mfma_f32_16x16x32_bf16(A1, Brh, r_, 0, 0, 0);
                r_ = __builtin_amdgcn_mfma_f32_16x16x32_bf16(A4, Bih, r_, 0, 0, 0);
                r_ = __builtin_amdgcn_mfma_f32_16x16x32_bf16(A4, Bil, r_, 0, 0, 0);
                r_ = __builtin_amdgcn_mfma_f32_16x16x32_bf16(A5, Bih, r_, 0, 0, 0);
                accR[rt] = r_;
                float4v i_ = accI[rt];
                i_ = __builtin_amdgcn_mfma_f32_16x16x32_bf16(A2, Brh, i_, 0, 0, 0);
                i_ = __builtin_amdgcn_mfma_f32_16x16x32_bf16(A2, Brl, i_, 0, 0, 0);
                i_ = __builtin_amdgcn_mfma_f32_16x16x32_bf16(A3, Brh, i_, 0, 0, 0);
                i_ = __builtin_amdgcn_mfma_f32_16x16x32_bf16(A0, Bih, i_, 0, 0, 0);
                i_ = __builtin_amdgcn_mfma_f32_16x16x32_bf16(A0, Bil, i_, 0, 0, 0);
                i_ = __builtin_amdgcn_mfma_f32_16x16x32_bf16(A1, Bih, i_, 0, 0, 0);
                accI[rt] = i_;
            }
        }
#pragma unroll
        for (int rt = 0; rt < RT_W; ++rt) {
            int rbase = (rt0 + rt) * 16 + rowq * 4;
#pragma unroll
            for (int q = 0; q < 4; ++q)
                Out[(size_t)(rbase + q) * P_ + p0 + colp] = make_float2(accR[rt][q], accI[rt][q]);
        }
    }
}

// MFMA contract, phase A.
__global__ __launch_bounds__(256) void k_contractA(const float2* __restrict__ XF,
                                                   const unsigned short* __restrict__ bA,
                                                   const unsigned short* __restrict__ gB,
                                                   unsigned short* __restrict__ tA) {
    int t = threadIdx.x;
    int k = blockIdx.x >> 2;
    int ytile = blockIdx.x & 3;
    int y0 = ytile << 4;
    int reg = (k >= 64) ? 1 : 0;
    int x = k & 63;
    int itile = t >> 6, lane = t & 63;
    int ylane = lane & 15, qg = lane >> 4;

    const short8v* gBv = (const short8v*)gB;
    short8v g_r  = gBv[(((size_t)(0 * 2 + reg) * 64 + x) * 4 + ytile) * 64 + lane];
    short8v g_i  = gBv[(((size_t)(1 * 2 + reg) * 64 + x) * 4 + ytile) * 64 + lane];
    short8v g_ni = gBv[(((size_t)(2 * 2 + reg) * 64 + x) * 4 + ytile) * 64 + lane];

    const short8v* bAv = (const short8v*)bA;
    size_t aR = (((size_t)(0 * 2 + reg) * 4 + itile) * 128) * 64 + lane;
    size_t aI = (((size_t)(1 * 2 + reg) * 4 + itile) * 128) * 64 + lane;

    const float2* xfp = XF + (size_t)k * 32768 + y0 + ylane;

    float tr[4][4], ti[4][4];
#pragma unroll
    for (int q = 0; q < 4; ++q)
#pragma unroll
        for (int b = 0; b < 4; ++b) { tr[q][b] = 0.f; ti[q][b] = 0.f; }

#pragma unroll 2
    for (int c = 0; c < 128; ++c) {
        short8v av = bAv[aR + (size_t)c * 64];
        short8v aw = bAv[aI + (size_t)c * 64];
        float4v z4 = {0.f, 0.f, 0.f, 0.f};
        float4v wr = __builtin_amdgcn_mfma_f32_16x16x32_bf16(av, g_r, z4, 0, 0, 0);
        wr = __builtin_amdgcn_mfma_f32_16x16x32_bf16(aw, g_ni, wr, 0, 0, 0);
        float4v wi = __builtin_amdgcn_mfma_f32_16x16x32_bf16(av, g_i, z4, 0, 0, 0);
        wi = __builtin_amdgcn_mfma_f32_16x16x32_bf16(aw, g_r, wi, 0, 0, 0);
#pragma unroll
        for (int b = 0; b < 4; ++b) {
            float2 xv = xfp[(size_t)b * 8192 + (size_t)c * 64];
#pragma unroll
            for (int q = 0; q < 4; ++q) {
                tr[q][b] = fmaf(wr[q], xv.x, fmaf(-wi[q], xv.y, tr[q][b]));
                ti[q][b] = fmaf(wr[q], xv.y, fmaf( wi[q], xv.x, ti[q][b]));
            }
        }
    }

    short* tAs = (short*)tA;
    const size_t PLT = (size_t)8 * 32768 * 8;
    int gidx = itile * 2 + (qg >> 1);
    int e0 = (qg & 1) * 4;
#pragma unroll
    for (int b = 0; b < 4; ++b) {
        size_t col = (size_t)k * 256 + (size_t)b * 64 + y0 + ylane;
        size_t off = ((size_t)gidx * 32768 + col) * 8 + e0;
        short rh[4], rl[4], ih[4], il[4];
#pragma unroll
        for (int q = 0; q < 4; ++q) {
            unsigned short h1 = f2bf(tr[q][b]);
            rh[q] = (short)h1; rl[q] = (short)f2bf(tr[q][b] - bf2f(h1));
            unsigned short h2 = f2bf(ti[q][b]);
            ih[q] = (short)h2; il[q] = (short)f2bf(ti[q][b] - bf2f(h2));
        }
        *(short4*)&tAs[0 * PLT + off] = make_short4(rh[0], rh[1], rh[2], rh[3]);
        *(short4*)&tAs[1 * PLT + off] = make_short4(rl[0], rl[1], rl[2], rl[3]);
        *(short4*)&tAs[2 * PLT + off] = make_short4(ih[0], ih[1], ih[2], ih[3]);
        *(short4*)&tAs[3 * PLT + off] = make_short4(il[0], il[1], il[2], il[3]);
    }
}

// MFMA contract, phase B.
__global__ __launch_bounds__(256) void k_amfma(const unsigned short* __restrict__ AFa,
                                               const unsigned short* __restrict__ tA,
                                               float2* __restrict__ OF) {
    constexpr int SG = 8;
    __shared__ __align__(16) unsigned short bs[4 * SG * 16 * 8];
    int t = threadIdx.x;
    int wave = t >> 6, lane = t & 63;
    int rt0 = wave * 2;
    int colp = lane & 15, rowq = lane >> 4;
    int k = blockIdx.x >> 2, b = blockIdx.x & 3;
    int reg = (k >= 64) ? 1 : 0;
    const short8v* AFv = (const short8v*)(AFa + (size_t)reg * 6 * 2 * 8 * 512);
    const size_t PLA = 2 * 8 * 64;
    const short8v* bsv = (const short8v*)bs;
    size_t p0 = (size_t)blockIdx.x * 64;

    for (int pt = 0; pt < 4; ++pt) {
        __syncthreads();
        {
            const float4* src = (const float4*)tA;
            float4* dst = (float4*)bs;
            for (int e = t; e < 4 * SG * 16; e += 256) {
                int pl = e >> 7; int rem = e & 127;
                int g = rem >> 4, li = rem & 15;
                dst[e] = src[((size_t)pl * SG + g) * 32768 + p0 + pt * 16 + li];
            }
        }
        __syncthreads();
        float4v accR[2], accI[2];
#pragma unroll
        for (int rt = 0; rt < 2; ++rt) {
            accR[rt] = (float4v){0.f, 0.f, 0.f, 0.f};
            accI[rt] = (float4v){0.f, 0.f, 0.f, 0.f};
        }
#pragma unroll
        for (int kc = 0; kc < 2; ++kc) {
            int gi = kc * 4 + rowq;
            short8v Brh = bsv[((0 * SG + gi) << 4) + colp];
            short8v Brl = bsv[((1 * SG + gi) << 4) + colp];
            short8v Bih = bsv[((2 * SG + gi) << 4) + colp];
            short8v Bil = bsv[((3 * SG + gi) << 4) + colp];
#pragma unroll
            for (int rt = 0; rt < 2; ++rt) {
                size_t ab = ((size_t)kc * 8 + rt0 + rt) * 64 + lane;
                short8v A0 = AFv[0 * PLA + ab];
                short8v A1 = AFv[1 * PLA + ab];
                short8v A2 = AFv[2 * PLA + ab];
                short8v A3 = AFv[3 * PLA + ab];
                short8v A4 = AFv[4 * PLA + ab];
                short8v A5 = AFv[5 * PLA + ab];
                float4v r_ = accR[rt];
                r_ = __builtin_amdgcn_mfma_f32_16x16x32_bf16(A0, Brh, r_, 0, 0, 0);
                r_ = __builtin_amdgcn_mfma_f32_16x16x32_bf16(A0, Brl, r_, 0, 0, 0);
                r_ = __builtin_amdgcn_mfma_f32_16x16x32_bf16(A1, Brh, r_, 0, 0, 0);
                r_ = __builtin_amdgcn_mfma_f32_16x16x32_bf16(A4, Bih, r_, 0, 0, 0);
                r_ = __builtin_amdgcn_mfma_f32_16x16x32_bf16(A4, Bil, r_, 0, 0, 0);
                r_ = __builtin_amdgcn_mfma_f32_16x16x32_bf16(A5, Bih, r_, 0, 0, 0);
                accR[rt] = r_;
                float4v i_ = accI[rt];
                i_ = __builtin_amdgcn_mfma_f32_16x16x32_bf16(A2, Brh, i_, 0, 0, 0);
                i_ = __builtin_amdgcn_mfma_f32_16x16x32_bf16(A2, Brl, i_, 0, 0, 0);
                i_ = __builtin_amdgcn_mfma_f32_16x16x32_bf16(A3, Brh, i_, 0, 0, 0);
                i_ = __builtin_amdgcn_mfma_f32_16x16x32_bf16(A0, Bih, i_, 0, 0, 0);
                i_ = __builtin_amdgcn_mfma_f32_16x16x32_bf16(A0, Bil, i_, 0, 0, 0);
                i_ = __builtin_amdgcn_mfma_f32_16x16x32_bf16(A1, Bih, i_, 0, 0, 0);
                accI[rt] = i_;
            }
        }
        int m = pt * 16 + colp;
#pragma unroll
        for (int rt = 0; rt < 2; ++rt) {
            int o0 = (rt0 + rt) * 16 + rowq * 4;
#pragma unroll
            for (int q = 0; q < 4; ++q)
                OF[(size_t)k * 32768 + (size_t)b * 8192 + (size_t)(o0 + q) * 64 + m] =
                    make_float2(accR[rt][q], accI[rt][q]);
        }
    }
}

// OF fp32 [k][p] -> OFt 4 bf16 planes [k>>3][p][k&7]
__global__ __launch_bounds__(256) void k_repack(const float2* __restrict__ OF,
                                                unsigned short* __restrict__ OFt) {
    int t = threadIdx.x;
    size_t p = (size_t)blockIdx.x * 256 + t;
    int kg = blockIdx.y;
    short8v vrh, vrl, vih, vil;
#pragma unroll
    for (int j = 0; j < 8; ++j) {
        float2 v = OF[(size_t)(kg * 8 + j) * P_ + p];
        unsigned short h1 = f2bf(v.x);
        vrh[j] = (short)h1; vrl[j] = (short)f2bf(v.x - bf2f(h1));
        unsigned short h2 = f2bf(v.y);
        vih[j] = (short)h2; vil[j] = (short)f2bf(v.y - bf2f(h2));
    }
    short8v* dst = (short8v*)OFt;
    const size_t PL8 = (size_t)16 * 32768;
    size_t gi = (size_t)kg * 32768 + p;
    dst[0 * PL8 + gi] = vrh;
    dst[1 * PL8 + gi] = vrl;
    dst[2 * PL8 + gi] = vih;
    dst[3 * PL8 + gi] = vil;
}

// MFMA inverse W-DFT: out[(bo,h)][w] = Re(Z . E).
// Wave = one 16-row M-tile (16 consecutive bo at fixed h); Z split hi/lo on the fly;
// E staged in LDS (FULL 64 KB = 4096 float4 = 16 x 256), 4 MFMAs per (nt,kc).
__global__ __launch_bounds__(256) void k_invWm(const float2* __restrict__ Z,
                                               const unsigned short* __restrict__ EF,
                                               float* __restrict__ out) {
    __shared__ __align__(16) unsigned short es[32768];   // 64 KB
    int t = threadIdx.x;
    {
        const float4* src = (const float4*)EF;
        float4* dst = (float4*)es;
#pragma unroll
        for (int i = 0; i < 16; ++i) dst[t + 256 * i] = src[t + 256 * i];   // 4096 f4 = 64 KB
    }
    __syncthreads();
    int wave = t >> 6, lane = t & 63;
    int colp = lane & 15, rowq = lane >> 4;
    int m = blockIdx.x * 4 + wave;           // mtile id (131072/16 = 8192)
    int h = m >> 5, bot = m & 31;

    short8v Zrh[2], Zrl[2], Zih[2], Zil[2];
    const float2* zp = Z + (size_t)h * 32768 + (size_t)(bot * 16 + colp) * 64;
#pragma unroll
    for (int kc = 0; kc < 2; ++kc) {
        const float4* zv = (const float4*)(zp + kc * 32 + 8 * rowq);
        float4 a = zv[0], b = zv[1], c = zv[2], d = zv[3];
        float re[8] = {a.x, a.z, b.x, b.z, c.x, c.z, d.x, d.z};
        float im[8] = {a.y, a.w, b.y, b.w, c.y, c.w, d.y, d.w};
#pragma unroll
        for (int j = 0; j < 8; ++j) {
            unsigned short h1 = f2bf(re[j]);
            Zrh[kc][j] = (short)h1; Zrl[kc][j] = (short)f2bf(re[j] - bf2f(h1));
            unsigned short h2 = f2bf(im[j]);
            Zih[kc][j] = (short)h2; Zil[kc][j] = (short)f2bf(im[j] - bf2f(h2));
        }
    }

    const short8v* esv = (const short8v*)es;
    size_t obase = ((size_t)(bot * 16 + rowq * 4) * 256 + h) * 256;
#pragma unroll
    for (int nt = 0; nt < 16; ++nt) {
        float4v acc = {0.f, 0.f, 0.f, 0.f};
#pragma unroll
        for (int kc = 0; kc < 2; ++kc) {
            short8v Er  = esv[((0 * 2 + kc) * 16 + nt) * 64 + lane];
            short8v nEi = esv[((1 * 2 + kc) * 16 + nt) * 64 + lane];
            acc = __builtin_amdgcn_mfma_f32_16x16x32_bf16(Zrh[kc], Er,  acc, 0, 0, 0);
            acc = __builtin_amdgcn_mfma_f32_16x16x32_bf16(Zrl[kc], Er,  acc, 0, 0, 0);
            acc = __builtin_amdgcn_mfma_f32_16x16x32_bf16(Zih[kc], nEi, acc, 0, 0, 0);
            acc = __builtin_amdgcn_mfma_f32_16x16x32_bf16(Zil[kc], nEi, acc, 0, 0, 0);
        }
        int w = nt * 16 + colp;
#pragma unroll
        for (int q = 0; q < 4; ++q)
            out[obase + (size_t)q * 65536 + w] = acc[q];
    }
}

extern "C" void kernel_launch(void* const* d_in, const int* in_sizes, int n_in,
                              void* d_out, int out_size, void* d_ws, size_t ws_size,
                              hipStream_t stream) {
    const float* x  = (const float*)d_in[0];
    const float* a1 = (const float*)d_in[1];
    const float* b1 = (const float*)d_in[2];
    const float* c1 = (const float*)d_in[3];
    const float* d1 = (const float*)d_in[4];
    const float* a2 = (const float*)d_in[5];
    const float* b2 = (const float*)d_in[6];
    const float* c2 = (const float*)d_in[7];
    const float* d2 = (const float*)d_in[8];
    float* out = (float*)d_out;
    float* wsf = (float*)d_ws;

    if (ws_size < WS_FLOATS * sizeof(float)) return;

    unsigned short* Yt  = (unsigned short*)(wsf + oYT);
    float2*         Zb  = (float2*)(wsf + oYT);          // Z aliases Yt region (after amfma)
    float2*         XF  = (float2*)(wsf + oXF);
    unsigned short* OFt = (unsigned short*)(wsf + oXF);  // OFt aliases XF (after contractA)
    float2*         OF  = (float2*)(wsf + oOF);
    unsigned short* EF  = (unsigned short*)(wsf + oOF);  // EF aliases OF (after repack)
    float2*         G   = (float2*)(wsf + oG);
    unsigned short* BF  = (unsigned short*)(wsf + oBF);
    unsigned short* AF1 = (unsigned short*)(wsf + oAF1);
    unsigned short* AF2 = (unsigned short*)(wsf + oAF2);
    unsigned short* bA  = (unsigned short*)(wsf + oYT);  // after cmfma1, Yt region is dead
    unsigned short* gB  = bA + 1048576;
    unsigned short* tA  = (unsigned short*)(wsf + oTA);
    unsigned short* AFa = (unsigned short*)(wsf + oG);   // overwrites G after prepBG

    k_prepT<<<1792, 256, 0, stream>>>(AF1, AF2, BF);
    k_g<<<1024, 256, 0, stream>>>(c1, d1, c2, d2, G);
    k_stage1m<<<1024, 256, 0, stream>>>(x, BF, Yt);
    k_cmfma<256, 2><<<512, 256, 0, stream>>>(AF1, Yt, XF);
    k_prepBG<<<7168, 256, 0, stream>>>(b1, b2, G, bA, gB);
    k_prepA<<<384, 256, 0, stream>>>(a1, a2, AFa);       // G dead after prepBG
    k_contractA<<<512, 256, 0, stream>>>(XF, bA, gB, tA);
    k_amfma<<<512, 256, 0, stream>>>(AFa, tA, OF);
    k_repack<<<dim3(128, 16), 256, 0, stream>>>(OF, OFt);
    k_prepE<<<128, 256, 0, stream>>>(EF);                // OF dead after repack
    k_cmfma<128, 4><<<512, 256, 0, stream>>>(AF2, OFt, Zb);
    k_invWm<<<2048, 256, 0, stream>>>(Zb, EF, out);

    (void)in_sizes; (void)n_in; (void)out_size;
}